// Round 7
// baseline (1071.180 us; speedup 1.0000x reference)
//
#include <hip/hip_runtime.h>

#define Hdim  1024
#define Tdim  2048
#define Bdim  4
#define HUdim 4096
#define Mrows (Bdim*Tdim)   // 8192
#define CHUNK 2048          // HU processed in HUdim/CHUNK slices
#define NCH   (HUdim/CHUNK) // 2
#define NSEG  16            // T-segments for parallel scan
#define SEGL  (Tdim/NSEG)   // 128
#define SCHUNK 16

typedef __bf16 bf16;
typedef __bf16 bf16x2 __attribute__((ext_vector_type(2)));
typedef __bf16 bf16x8 __attribute__((ext_vector_type(8)));
typedef float  floatx4 __attribute__((ext_vector_type(4)));

__device__ __forceinline__ bf16 f2bf(float x) { return (bf16)x; }

// ---------------- fused weight transpose + f32->bf16 convert (all 7 weights) ----------------
__global__ __launch_bounds__(256) void wconv_all(
    const float* __restrict__ s0, const float* __restrict__ s1, const float* __restrict__ s2,
    const float* __restrict__ s3, const float* __restrict__ s4, const float* __restrict__ s5,
    const float* __restrict__ s6,
    bf16* d0, bf16* d1, bf16* d2, bf16* d3, bf16* d4, bf16* d5, bf16* d6) {
  __shared__ float tile[64][65];
  int bid = blockIdx.x;
  const float* src; bf16* dst; int K, N, local;
  if (bid < 1024)      { src = s0; dst = d0; K = Hdim;  N = HUdim; local = bid; }
  else if (bid < 2048) { src = s1; dst = d1; K = Hdim;  N = HUdim; local = bid - 1024; }
  else if (bid < 3072) { src = s2; dst = d2; K = Hdim;  N = HUdim; local = bid - 2048; }
  else if (bid < 4096) { src = s3; dst = d3; K = HUdim; N = Hdim;  local = bid - 3072; }
  else if (bid < 5120) { src = s4; dst = d4; K = Hdim;  N = HUdim; local = bid - 4096; }
  else if (bid < 6144) { src = s5; dst = d5; K = HUdim; N = Hdim;  local = bid - 5120; }
  else                 { src = s6; dst = d6; K = Hdim;  N = Hdim;  local = bid - 6144; }
  const int nt = N >> 6;
  const int n0 = (local % nt) * 64, k0 = (local / nt) * 64;
  const int tr = threadIdx.x >> 6;   // 0..3
  const int tc = threadIdx.x & 63;
#pragma unroll
  for (int j = 0; j < 16; j++) {
    int r = j * 4 + tr;
    tile[r][tc] = src[(size_t)(k0 + r) * N + n0 + tc];
  }
  __syncthreads();
#pragma unroll
  for (int j = 0; j < 16; j++) {
    int r = j * 4 + tr;
    dst[(size_t)(n0 + r) * K + k0 + tc] = f2bf(tile[tc][r]);
  }
}

// ---------------- block reduction helper (256 threads, 4 values) ----------------
__device__ __forceinline__ void block_reduce4(float v[4], float* sm) {
#pragma unroll
  for (int off = 32; off > 0; off >>= 1) {
#pragma unroll
    for (int i = 0; i < 4; i++) v[i] += __shfl_down(v[i], off, 64);
  }
  const int w = threadIdx.x >> 6;
  if ((threadIdx.x & 63) == 0) {
#pragma unroll
    for (int i = 0; i < 4; i++) sm[w * 4 + i] = v[i];
  }
  __syncthreads();
#pragma unroll
  for (int i = 0; i < 4; i++) v[i] = sm[i] + sm[4 + i] + sm[8 + i] + sm[12 + i];
  __syncthreads();
}

// ---------------- ln0 + pre-LN + shift + TM mixes ----------------
__global__ __launch_bounds__(256) void ln_mix_tm(
    const float* __restrict__ x,
    const float* __restrict__ g0, const float* __restrict__ b0,
    const float* __restrict__ g1, const float* __restrict__ b1,
    const float* __restrict__ mk, const float* __restrict__ mv, const float* __restrict__ mr,
    float* __restrict__ x0, bf16* __restrict__ xk, bf16* __restrict__ xv, bf16* __restrict__ xr) {
  __shared__ float sm[16];
  const int bid = blockIdx.x;
  const int t = bid & (Tdim - 1);
  const int tid = threadIdx.x;
  const bool havep = (t > 0);
  const float hp = havep ? 1.f : 0.f;
  const float* rowc = x + (size_t)bid * Hdim;
  const float* rowp = havep ? (rowc - Hdim) : rowc;  // always in-bounds

  float c[4], p[4];
#pragma unroll
  for (int j = 0; j < 4; j++) c[j] = rowc[tid * 4 + j];
#pragma unroll
  for (int j = 0; j < 4; j++) p[j] = rowp[tid * 4 + j] * hp;

  float red[4] = {0.f, 0.f, 0.f, 0.f};
#pragma unroll
  for (int j = 0; j < 4; j++) { red[0] += c[j]; red[1] += c[j]*c[j]; red[2] += p[j]; red[3] += p[j]*p[j]; }
  block_reduce4(red, sm);
  const float inv = 1.f / Hdim;
  float mc = red[0]*inv, vc = red[1]*inv - mc*mc;
  float mp = red[2]*inv, vp = red[3]*inv - mp*mp;
  float sc = rsqrtf(vc + 1e-5f), sp = rsqrtf(vp + 1e-5f);

  float yc[4], yp[4];
#pragma unroll
  for (int j = 0; j < 4; j++) {
    int i = tid * 4 + j;
    yc[j] = (c[j] - mc) * sc * g0[i] + b0[i];
    yp[j] = ((p[j] - mp) * sp * g0[i] + b0[i]) * hp;
    x0[(size_t)bid * Hdim + i] = yc[j];
  }

  float r2[4] = {0.f, 0.f, 0.f, 0.f};
#pragma unroll
  for (int j = 0; j < 4; j++) { r2[0] += yc[j]; r2[1] += yc[j]*yc[j]; r2[2] += yp[j]; r2[3] += yp[j]*yp[j]; }
  block_reduce4(r2, sm);
  float mc2 = r2[0]*inv, vc2 = r2[1]*inv - mc2*mc2;
  float mp2 = r2[2]*inv, vp2 = r2[3]*inv - mp2*mp2;
  float sc2 = rsqrtf(vc2 + 1e-5f), sp2 = rsqrtf(vp2 + 1e-5f);

#pragma unroll
  for (int j = 0; j < 4; j++) {
    int i = tid * 4 + j;
    float xnc = (yc[j] - mc2) * sc2 * g1[i] + b1[i];
    float xnp = ((yp[j] - mp2) * sp2 * g1[i] + b1[i]) * hp;
    size_t o = (size_t)bid * Hdim + i;
    float a;
    a = mk[i]; xk[o] = f2bf(xnc * a + xnp * (1.f - a));
    a = mv[i]; xv[o] = f2bf(xnc * a + xnp * (1.f - a));
    a = mr[i]; xr[o] = f2bf(xnc * a + xnp * (1.f - a));
  }
}

// ---------------- post-LN + shift + CM mixes ----------------
__global__ __launch_bounds__(256) void ln_mix_cm(
    const float* __restrict__ xin,
    const float* __restrict__ g, const float* __restrict__ bb,
    const float* __restrict__ mk, const float* __restrict__ mr,
    bf16* __restrict__ xk, bf16* __restrict__ xr) {
  __shared__ float sm[16];
  const int bid = blockIdx.x;
  const int t = bid & (Tdim - 1);
  const int tid = threadIdx.x;
  const bool havep = (t > 0);
  const float hp = havep ? 1.f : 0.f;
  const float* rowc = xin + (size_t)bid * Hdim;
  const float* rowp = havep ? (rowc - Hdim) : rowc;

  float c[4], p[4];
#pragma unroll
  for (int j = 0; j < 4; j++) c[j] = rowc[tid * 4 + j];
#pragma unroll
  for (int j = 0; j < 4; j++) p[j] = rowp[tid * 4 + j] * hp;

  float red[4] = {0.f, 0.f, 0.f, 0.f};
#pragma unroll
  for (int j = 0; j < 4; j++) { red[0] += c[j]; red[1] += c[j]*c[j]; red[2] += p[j]; red[3] += p[j]*p[j]; }
  block_reduce4(red, sm);
  const float inv = 1.f / Hdim;
  float mc = red[0]*inv, vc = red[1]*inv - mc*mc;
  float mp = red[2]*inv, vp = red[3]*inv - mp*mp;
  float sc = rsqrtf(vc + 1e-5f), sp = rsqrtf(vp + 1e-5f);

#pragma unroll
  for (int j = 0; j < 4; j++) {
    int i = tid * 4 + j;
    float xnc = (c[j] - mc) * sc * g[i] + bb[i];
    float xnp = ((p[j] - mp) * sp * g[i] + bb[i]) * hp;
    size_t o = (size_t)bid * Hdim + i;
    float a;
    a = mk[i]; xk[o] = f2bf(xnc * a + xnp * (1.f - a));
    a = mr[i]; xr[o] = f2bf(xnc * a + xnp * (1.f - a));
  }
}

// ---------------- WKV parallel scan (2 channels/thread, bf16x2 loads) ----------------
__global__ __launch_bounds__(64) void wkv_part(
    const bf16* __restrict__ Kb, const bf16* __restrict__ Vb,
    float* __restrict__ stK, float* __restrict__ stKV,
    const float* __restrict__ tdec) {
  const int seg = blockIdx.x & (NSEG - 1);
  const int rest = blockIdx.x >> 4;       // b*16 + g
  const int b = rest >> 4, g = rest & 15;
  const int c = (g << 7) + (threadIdx.x << 1);
  const float d0 = __expf(-__expf(tdec[c]));
  const float d1 = __expf(-__expf(tdec[c + 1]));
  size_t base = ((size_t)b * Tdim + (size_t)seg * SEGL) * CHUNK + c;
  float sk0 = 0.f, skv0 = 0.f, sk1 = 0.f, skv1 = 0.f;
  for (int t0 = 0; t0 < SEGL; t0 += SCHUNK) {
    bf16x2 kk[SCHUNK], vv[SCHUNK];
#pragma unroll
    for (int j = 0; j < SCHUNK; j++) {
      size_t idx = base + (size_t)(t0 + j) * CHUNK;
      kk[j] = *(const bf16x2*)(Kb + idx);
      vv[j] = *(const bf16x2*)(Vb + idx);
    }
#pragma unroll
    for (int j = 0; j < SCHUNK; j++) {
      float k0 = (float)kk[j][0], k1 = (float)kk[j][1];
      float v0 = (float)vv[j][0], v1 = (float)vv[j][1];
      sk0  = fmaf(d0, sk0, k0);   skv0 = fmaf(d0, skv0, k0 * v0);
      sk1  = fmaf(d1, sk1, k1);   skv1 = fmaf(d1, skv1, k1 * v1);
    }
  }
  size_t so = ((size_t)seg * Bdim + b) * CHUNK + c;
  stK[so]      = sk0;  stK[so + 1]  = sk1;
  stKV[so]     = skv0; stKV[so + 1] = skv1;
}

__global__ __launch_bounds__(64) void wkv_emit(
    const bf16* __restrict__ Kb, const bf16* __restrict__ Vb,
    const bf16* SRb, bf16* Pb,   // SRb/Pb alias: per-element read-before-write
    const float* __restrict__ stK, const float* __restrict__ stKV,
    const float* __restrict__ tdec, const float* __restrict__ tfst) {
  const int seg = blockIdx.x & (NSEG - 1);
  const int rest = blockIdx.x >> 4;
  const int b = rest >> 4, g = rest & 15;
  const int c = (g << 7) + (threadIdx.x << 1);
  const float ed0 = __expf(tdec[c]),     ed1 = __expf(tdec[c + 1]);
  const float d0  = __expf(-ed0),        d1  = __expf(-ed1);
  const float df0 = __expf(-ed0 * (float)SEGL);
  const float df1 = __expf(-ed1 * (float)SEGL);
  const float f0  = __expf(tfst[c]),     f1  = __expf(tfst[c + 1]);

  float sk0 = 0.f, skv0 = 0.f, sk1 = 0.f, skv1 = 0.f;
  for (int j = 0; j < seg; j++) {
    size_t so = ((size_t)j * Bdim + b) * CHUNK + c;
    sk0  = fmaf(df0, sk0,  stK[so]);      sk1  = fmaf(df1, sk1,  stK[so + 1]);
    skv0 = fmaf(df0, skv0, stKV[so]);     skv1 = fmaf(df1, skv1, stKV[so + 1]);
  }

  size_t base = ((size_t)b * Tdim + (size_t)seg * SEGL) * CHUNK + c;
  for (int t0 = 0; t0 < SEGL; t0 += SCHUNK) {
    bf16x2 kk[SCHUNK], vv[SCHUNK], rr[SCHUNK];
#pragma unroll
    for (int j = 0; j < SCHUNK; j++) {
      size_t idx = base + (size_t)(t0 + j) * CHUNK;
      kk[j] = *(const bf16x2*)(Kb + idx);
      vv[j] = *(const bf16x2*)(Vb + idx);
      rr[j] = *(const bf16x2*)(SRb + idx);
    }
#pragma unroll
    for (int j = 0; j < SCHUNK; j++) {
      size_t idx = base + (size_t)(t0 + j) * CHUNK;
      float k0 = (float)kk[j][0], k1 = (float)kk[j][1];
      float v0 = (float)vv[j][0], v1 = (float)vv[j][1];
      float kv0 = k0 * v0, kv1 = k1 * v1;
      float wk0  = fmaf(f0, k0, sk0) + 1e-8f;
      float wk1  = fmaf(f1, k1, sk1) + 1e-8f;
      float wkv0 = fmaf(f0, kv0, skv0);
      float wkv1 = fmaf(f1, kv1, skv1);
      bf16x2 out;
      out[0] = f2bf((float)rr[j][0] * wkv0 * __builtin_amdgcn_rcpf(wk0));
      out[1] = f2bf((float)rr[j][1] * wkv1 * __builtin_amdgcn_rcpf(wk1));
      *(bf16x2*)(Pb + idx) = out;
      sk0  = fmaf(d0, sk0, k0);   skv0 = fmaf(d0, skv0, kv0);
      sk1  = fmaf(d1, sk1, k1);   skv1 = fmaf(d1, skv1, kv1);
    }
  }
}

// ---------------- shared helpers ----------------
__device__ __forceinline__ void gld_lds(const bf16* g, bf16* l) {
  __builtin_amdgcn_global_load_lds(
      (const __attribute__((address_space(1))) void*)(g),
      (__attribute__((address_space(3))) void*)(l),
      16, 0, 0);
}

// XCD-aware swizzle: xcd=s%8 owns m-band; n in groups of 2, m fastest.
__device__ __forceinline__ void swz(int s, int gm, int& m_t, int& n_t) {
  const int mpx  = gm >> 3;        // gm % 8 == 0 at all call sites
  const int xcd  = s & 7;
  const int ss   = s >> 3;
  const int pass = mpx << 1;
  const int ng   = ss / pass;
  const int rem  = ss - ng * pass;
  m_t = xcd * mpx + (rem >> 1);
  n_t = (ng << 1) + (rem & 1);
}

enum { E_EXP = 0, E_BF16 = 1, E_SIG = 2, E_ADD1 = 3, E_SILU = 4, E_F32 = 5, E_SIGADD2 = 6 };

template <int EPI>
__device__ __forceinline__ void epilogue(
    floatx4 acc[4][4], void* Cout, const void* aux1, const void* aux2,
    long m0, long n0, int ldc, int lane, int wm, int wn) {
  const int r0 = wm * 64 + ((lane >> 4) << 2);
  const int c0 = wn * 64 + (lane & 15);
#pragma unroll
  for (int mt = 0; mt < 4; mt++) {
#pragma unroll
    for (int i = 0; i < 4; i++) {
      long r = m0 + r0 + mt * 16 + i;
      long bidx = r * (long)ldc + n0 + c0;
#pragma unroll
      for (int nt = 0; nt < 4; nt++) {
        long idx = bidx + nt * 16;
        float v = acc[mt][nt][i];
        if constexpr (EPI == E_EXP) {
          ((bf16*)Cout)[idx] = f2bf(__expf(fminf(v, 60.f)));
        } else if constexpr (EPI == E_BF16) {
          ((bf16*)Cout)[idx] = f2bf(v);
        } else if constexpr (EPI == E_SIG) {
          ((bf16*)Cout)[idx] = f2bf(1.f / (1.f + __expf(-v)));
        } else if constexpr (EPI == E_ADD1) {
          float prev = ((const float*)aux1)[idx];   // may alias Cout (same idx)
          ((float*)Cout)[idx] = v + prev;
        } else if constexpr (EPI == E_SILU) {
          ((bf16*)Cout)[idx] = f2bf(v / (1.f + __expf(-v)));
        } else if constexpr (EPI == E_F32) {
          ((float*)Cout)[idx] = v;
        } else {  // E_SIGADD2
          float a1 = ((const float*)aux1)[idx];
          float a2 = ((const float*)aux2)[idx];
          ((float*)Cout)[idx] = a1 + 1.f / (1.f + __expf(-v)) + a2;
        }
      }
    }
  }
}

// =====================================================================================
// 256x128-tile GEMM core, BK=64, TRIPLE-buffered LDS (3 x 48 KiB = 144 KiB), 8 waves
// (4M x 2N, 64x64 output each), ONE barrier + ONE counted vmcnt per K-iter.
// (R4 version — measured good.)
// =====================================================================================
__device__ __forceinline__ void mm_core_n128(
    const bf16* __restrict__ A, const bf16* __restrict__ Bt,
    int lda, int ldb, int K, long m0, long n0,
    int wv, int lane, bf16* Lds, floatx4 acc[4][4]) {
  const int rl  = lane >> 2;
  const int scol = (((lane & 3) - ((lane >> 3) & 3)) & 3) * 8;  // phase-swizzled k-slot
  const bf16* gA = A + (m0 + wv * 16 + rl) * (long)lda + scol;
  const bf16* gB = Bt + (n0 + wv * 16 + rl) * (long)ldb + scol;
  bf16* lA = Lds + wv * 512;            // + buf*16384 + h*4096; second k-panel +8192
  bf16* lB = Lds + 49152 + wv * 512;    // + buf*8192;           second k-panel +4096

  const int wm = wv >> 1, wn = wv & 1;
  const int pg = ((lane >> 4) + ((lane >> 1) & 3)) & 3;
  const bf16* fa0 = Lds + (wm * 64 + (lane & 15)) * 32 + pg * 8;
  const bf16* fb0 = Lds + 49152 + (wn * 64 + (lane & 15)) * 32 + pg * 8;

#define STGA_N(buf, h, kt) do { \
    const bf16* _s = gA + (long)(h) * 128 * lda + (long)(kt) * 64; \
    bf16* _d = lA + (buf) * 16384 + (h) * 4096; \
    gld_lds(_s, _d); gld_lds(_s + 32, _d + 8192); } while (0)
#define STGB_N(buf, kt) do { \
    const bf16* _s = gB + (long)(kt) * 64; \
    bf16* _d = lB + (buf) * 8192; \
    gld_lds(_s, _d); gld_lds(_s + 32, _d + 4096); } while (0)

  STGA_N(0, 0, 0); STGA_N(0, 1, 0); STGB_N(0, 0);
  STGA_N(1, 0, 1); STGA_N(1, 1, 1); STGB_N(1, 1);
  asm volatile("s_waitcnt vmcnt(6)" ::: "memory");
  __builtin_amdgcn_s_barrier();

  const int niter = K >> 6;            // K % 64 == 0
  int p = 0;
  for (int it = 0; it < niter; ++it) {
    const int q = (p >= 1) ? p - 1 : p + 2;      // (p+2)%3
    const bool dostage = (it <= niter - 3);
    const bf16* fa = fa0 + p * 16384;
    const bf16* fb = fb0 + p * 8192;

    // ---- kh = 0 ----
    bf16x8 a0[4], b0v[4];
#pragma unroll
    for (int i = 0; i < 4; ++i) {
      a0[i]  = *(const bf16x8*)(fa + i * 512);
      b0v[i] = *(const bf16x8*)(fb + i * 512);
    }
    __builtin_amdgcn_sched_barrier(0);
    if (dostage) { STGA_N(q, 0, it + 2); STGA_N(q, 1, it + 2); }
    asm volatile("s_waitcnt lgkmcnt(0)" ::: "memory");
    __builtin_amdgcn_s_setprio(1);
#pragma unroll
    for (int mf = 0; mf < 4; ++mf)
#pragma unroll
      for (int nf = 0; nf < 4; ++nf)
        acc[mf][nf] = __builtin_amdgcn_mfma_f32_16x16x32_bf16(a0[mf], b0v[nf], acc[mf][nf], 0, 0, 0);
    __builtin_amdgcn_s_setprio(0);

    // ---- kh = 1 ----
    bf16x8 a1[4], b1v[4];
#pragma unroll
    for (int i = 0; i < 4; ++i) {
      a1[i]  = *(const bf16x8*)(fa + 8192 + i * 512);
      b1v[i] = *(const bf16x8*)(fb + 4096 + i * 512);
    }
    __builtin_amdgcn_sched_barrier(0);
    if (dostage) STGB_N(q, it + 2);
    asm volatile("s_waitcnt lgkmcnt(0)" ::: "memory");
    __builtin_amdgcn_s_setprio(1);
#pragma unroll
    for (int mf = 0; mf < 4; ++mf)
#pragma unroll
      for (int nf = 0; nf < 4; ++nf)
        acc[mf][nf] = __builtin_amdgcn_mfma_f32_16x16x32_bf16(a1[mf], b1v[nf], acc[mf][nf], 0, 0, 0);
    __builtin_amdgcn_s_setprio(0);

    if (it < niter - 1) {
      if (dostage) asm volatile("s_waitcnt vmcnt(6)" ::: "memory");
      else         asm volatile("s_waitcnt vmcnt(0)" ::: "memory");
      __builtin_amdgcn_s_barrier();
    }
    p = (p == 2) ? 0 : p + 1;
  }
#undef STGA_N
#undef STGB_N
}

// 256x128-tile kernel: grid = (M/256)*(N/128) blocks.
template <int EPI>
__global__ __launch_bounds__(512, 2) void gemm8n(
    const bf16* __restrict__ A, const bf16* __restrict__ Bt,
    void* Cout, const void* aux1, const void* aux2,
    int lda, int ldb, int ldc, int K, int gm, int gn) {
  __shared__ __align__(16) bf16 Lds[73728];   // 144 KiB
  const int tid = threadIdx.x;
  const int lane = tid & 63;
  const int wv = tid >> 6;
  int m_t, n_t;
  swz(blockIdx.x, gm, m_t, n_t);
  const long m0 = (long)m_t * 256, n0 = (long)n_t * 128;
  floatx4 acc[4][4];
#pragma unroll
  for (int i = 0; i < 4; i++)
#pragma unroll
    for (int j = 0; j < 4; j++) acc[i][j] = (floatx4){0.f, 0.f, 0.f, 0.f};
  mm_core_n128(A, Bt, lda, ldb, K, m0, n0, wv, lane, Lds, acc);
  const int wm = wv >> 1, wn = wv & 1;   // 4M x 2N waves, 64x64 each
  epilogue<EPI>(acc, Cout, aux1, aux2, m0, n0, ldc, lane, wm, wn);
}

// =====================================================================================
// 256x256 8-phase core, refactored for PERSISTENT multi-tile blocks:
//  - stage_pro256(): the 7-half-tile prologue (14 loads), issued by the caller either
//    at kernel start or BEFORE the previous tile's epilogue (cross-tile prefetch).
//  - core256_loop(): the proven zigzag 8-phase K-loop, instruction-identical to R2/R4.
// Boundary wait derivation: after {stage_pro256 (14 loads, oldest) ; epilogue (128
// stores)}, s_waitcnt vmcnt(10) leaves <=10 outstanding, all of which are the NEWEST
// ops (stores) => all 14 staged loads retired — strictly STRONGER than the original
// prologue's vmcnt(10) guarantee. Stores deeper in the queue only add retirement
// pressure; a counted wait can never under-wait a load older than the window.
// =====================================================================================
__device__ __forceinline__ void stgA8(const bf16* gA, bf16* lA, int lda, int buf, int h, int kt) {
  const bf16* s = gA + (long)h * 64 * lda + kt * 64;
  bf16* d = lA + buf * 32768 + h * 2048;
  gld_lds(s, d); gld_lds(s + 32, d + 8192);
}
__device__ __forceinline__ void stgB8(const bf16* gB, bf16* lB, int ldb, int buf, int h, int kt) {
  const bf16* s = gB + (long)h * 32 * ldb + kt * 64;
  bf16* d = lB + buf * 32768 + h * 1024;
  gld_lds(s, d); gld_lds(s + 32, d + 8192);
}
__device__ __forceinline__ void stage_pro256(const bf16* gA, const bf16* gB, int lda, int ldb,
                                             bf16* lA, bf16* lB) {
  // buf0 all of kt=0 (read order), buf1 {A-h0, B-h0, B-h1} of kt=1.
  stgA8(gA, lA, lda, 0, 0, 0); stgB8(gB, lB, ldb, 0, 0, 0);
  stgB8(gB, lB, ldb, 0, 1, 0); stgA8(gA, lA, lda, 0, 1, 0);
  stgA8(gA, lA, lda, 1, 0, 1); stgB8(gB, lB, ldb, 1, 0, 1); stgB8(gB, lB, ldb, 1, 1, 1);
}

__device__ __forceinline__ void core256_loop(
    const bf16* gA, const bf16* gB, int lda, int ldb, int K,
    const bf16* fa0, const bf16* fb0, bf16* lA, bf16* lB, floatx4 acc[8][4]) {
  const int niter = K >> 7;            // K % 128 == 0
  bf16x8 a[4][2];
  bf16x8 b[2][2][2];
  for (int it = 0; it < niter; ++it) {
    const int kt0 = it << 1;
    const bool notlast = (it != niter - 1);
#pragma unroll
    for (int ph = 0; ph < 8; ++ph) {
      const int q   = ph & 3;
      const int buf = ph >> 2;
      const int mq  = q >> 1;
      const int nq  = (q >> 1) ^ (q & 1);
      const bf16* fa = fa0 + buf * 32768 + mq * 2048;
      const bf16* fb = fb0 + buf * 32768 + nq * 1024;
      if (q == 0) {
#pragma unroll
        for (int mf = 0; mf < 4; ++mf) {
          a[mf][0] = *(const bf16x8*)(fa + mf * 512);
          a[mf][1] = *(const bf16x8*)(fa + mf * 512 + 8192);
        }
#pragma unroll
        for (int nf = 0; nf < 2; ++nf) {
          b[0][nf][0] = *(const bf16x8*)(fb + nf * 512);
          b[0][nf][1] = *(const bf16x8*)(fb + nf * 512 + 8192);
        }
      } else if (q == 1) {
#pragma unroll
        for (int nf = 0; nf < 2; ++nf) {
          b[1][nf][0] = *(const bf16x8*)(fb + nf * 512);
          b[1][nf][1] = *(const bf16x8*)(fb + nf * 512 + 8192);
        }
      } else if (q == 2) {
#pragma unroll
        for (int mf = 0; mf < 4; ++mf) {
          a[mf][0] = *(const bf16x8*)(fa + mf * 512);
          a[mf][1] = *(const bf16x8*)(fa + mf * 512 + 8192);
        }
      }
      __builtin_amdgcn_sched_barrier(0);
      if (ph == 0)            stgA8(gA, lA, lda, 1, 1, kt0 + 1);   // always in-tile
      else if (notlast) {
        if (ph == 1)      stgA8(gA, lA, lda, 0, 0, kt0 + 2);
        else if (ph == 2) stgB8(gB, lB, ldb, 0, 0, kt0 + 2);
        else if (ph == 3) stgB8(gB, lB, ldb, 0, 1, kt0 + 2);
        else if (ph == 4) stgA8(gA, lA, lda, 0, 1, kt0 + 2);
        else if (ph == 5) stgA8(gA, lA, lda, 1, 0, kt0 + 3);
        else if (ph == 6) stgB8(gB, lB, ldb, 1, 0, kt0 + 3);
        else              stgB8(gB, lB, ldb, 1, 1, kt0 + 3);
      }
      if (notlast) {
        if (ph == 0 || ph == 1 || ph == 4 || ph == 5)
          asm volatile("s_waitcnt vmcnt(10)" ::: "memory");
        else if (ph == 3 || ph == 7)
          asm volatile("s_waitcnt vmcnt(12)" ::: "memory");
      } else {
        if (ph == 0)      asm volatile("s_waitcnt vmcnt(10)" ::: "memory");
        else if (ph == 1) asm volatile("s_waitcnt vmcnt(0)" ::: "memory");
      }
      if (q != 3) {
        __builtin_amdgcn_s_barrier();
        asm volatile("s_waitcnt lgkmcnt(0)" ::: "memory");
      }
      __builtin_amdgcn_s_setprio(1);
#pragma unroll
      for (int mf = 0; mf < 4; ++mf)
#pragma unroll
        for (int nf = 0; nf < 2; ++nf) {
          acc[mq*4+mf][nq*2+nf] = __builtin_amdgcn_mfma_f32_16x16x32_bf16(
              a[mf][0], b[nq][nf][0], acc[mq*4+mf][nq*2+nf], 0, 0, 0);
          acc[mq*4+mf][nq*2+nf] = __builtin_amdgcn_mfma_f32_16x16x32_bf16(
              a[mf][1], b[nq][nf][1], acc[mq*4+mf][nq*2+nf], 0, 0, 0);
        }
      __builtin_amdgcn_s_setprio(0);
      __builtin_amdgcn_s_barrier();
    }
  }
}

// ---------------- persistent 3-tile K/V/R projection (256 blocks, 256^2 tiles) ----------------
// Block b -> tiles (sub=0,1,2) at the SAME swz position. Next tile's prologue issues
// before this tile's epilogue; boundary = vmcnt(10)+barrier (see derivation above).
__global__ __launch_bounds__(512, 2) void proj8p(
    const bf16* __restrict__ xk, const bf16* __restrict__ xv, const bf16* __restrict__ xr,
    const bf16* __restrict__ Wk, const bf16* __restrict__ Wv, const bf16* __restrict__ Wr,
    bf16* Kc, bf16* Vc, bf16* SRc, int gm, int gn) {
  __shared__ __align__(16) bf16 Lds[65536];   // 128 KiB
  const int tid = threadIdx.x;
  const int lane = tid & 63;
  const int wv = tid >> 6;
  int m_t, n_t;
  swz(blockIdx.x, gm, m_t, n_t);
  const long m0 = (long)m_t * 256, n0 = (long)n_t * 256;
  const int wm = wv >> 2, wn = wv & 3;
  const int rA0 = wm * 128 + (wv & 3) * 16;
  const int rB0 = (wv >> 1) * 64 + (wv & 1) * 16;
  const int rl  = lane >> 2;
  const int scol = (((lane & 3) - ((lane >> 3) & 3)) & 3) * 8;
  bf16* lA = Lds + rA0 * 32;
  bf16* lB = Lds + 16384 + rB0 * 32;
  const int pg = ((lane >> 4) + ((lane >> 1) & 3)) & 3;
  const bf16* fa0 = Lds + (wm * 128 + (lane & 15)) * 32 + pg * 8;
  const bf16* fb0 = Lds + 16384 + (wn * 64 + (lane & 15)) * 32 + pg * 8;

  const long aoff = (m0 + rA0 + rl) * (long)Hdim + scol;
  const long boff = (n0 + rB0 + rl) * (long)Hdim + scol;
  const bf16* gA0 = xk + aoff;  const bf16* gB0 = Wk + boff;
  const bf16* gA1 = xv + aoff;  const bf16* gB1 = Wv + boff;
  const bf16* gA2 = xr + aoff;  const bf16* gB2 = Wr + boff;

  stage_pro256(gA0, gB0, Hdim, Hdim, lA, lB);
  asm volatile("s_waitcnt vmcnt(10)" ::: "memory");
  __builtin_amdgcn_s_barrier();

  const int r0 = wm * 128 + ((lane >> 4) << 2);
  const int c0 = wn * 64 + (lane & 15);

#pragma unroll 1
  for (int sub = 0; sub < 3; ++sub) {
    const bf16* gA = (sub == 0) ? gA0 : (sub == 1) ? gA1 : gA2;
    const bf16* gB = (sub == 0) ? gB0 : (sub == 1) ? gB1 : gB2;
    floatx4 acc[8][4];
#pragma unroll
    for (int i = 0; i < 8; i++)
#pragma unroll
      for (int j = 0; j < 4; j++) acc[i][j] = (floatx4){0.f, 0.f, 0.f, 0.f};
    core256_loop(gA, gB, Hdim, Hdim, Hdim, fa0, fb0, lA, lB, acc);

    // cross-tile prefetch: next tile's prologue hides under this tile's epilogue
    if (sub == 0)      stage_pro256(gA1, gB1, Hdim, Hdim, lA, lB);
    else if (sub == 1) stage_pro256(gA2, gB2, Hdim, Hdim, lA, lB);

    bf16* C = (sub == 0) ? Kc : (sub == 1) ? Vc : SRc;
#pragma unroll
    for (int mf = 0; mf < 8; ++mf) {
#pragma unroll
      for (int i = 0; i < 4; ++i) {
        long r = m0 + r0 + mf * 16 + i;
        long bidx = r * (long)CHUNK + n0 + c0;
#pragma unroll
        for (int nf = 0; nf < 4; ++nf) {
          float v = acc[mf][nf][i];
          float o = (sub == 0) ? __expf(fminf(v, 60.f))
                  : (sub == 1) ? v
                  : 1.f / (1.f + __expf(-v));
          C[bidx + nf * 16] = f2bf(o);
        }
      }
    }
    if (sub < 2) {
      asm volatile("s_waitcnt vmcnt(10)" ::: "memory");
      __builtin_amdgcn_s_barrier();
    }
  }
}

// ---------------- persistent 2-tile 256^2 GEMM (silu): tiles b and b+gridDim ----------------
template <int EPI>
__global__ __launch_bounds__(512, 2) void gemm8p2(
    const bf16* __restrict__ A, const bf16* __restrict__ Bt,
    void* Cout, int lda, int ldb, int ldc, int K, int gm, int gn) {
  __shared__ __align__(16) bf16 Lds[65536];   // 128 KiB
  const int tid = threadIdx.x;
  const int lane = tid & 63;
  const int wv = tid >> 6;
  int mt0, nt0, mt1, nt1;
  swz(blockIdx.x, gm, mt0, nt0);
  swz(blockIdx.x + (int)gridDim.x, gm, mt1, nt1);
  const long m0_0 = (long)mt0 * 256, n0_0 = (long)nt0 * 256;
  const long m0_1 = (long)mt1 * 256, n0_1 = (long)nt1 * 256;
  const int wm = wv >> 2, wn = wv & 3;
  const int rA0 = wm * 128 + (wv & 3) * 16;
  const int rB0 = (wv >> 1) * 64 + (wv & 1) * 16;
  const int rl  = lane >> 2;
  const int scol = (((lane & 3) - ((lane >> 3) & 3)) & 3) * 8;
  bf16* lA = Lds + rA0 * 32;
  bf16* lB = Lds + 16384 + rB0 * 32;
  const int pg = ((lane >> 4) + ((lane >> 1) & 3)) & 3;
  const bf16* fa0 = Lds + (wm * 128 + (lane & 15)) * 32 + pg * 8;
  const bf16* fb0 = Lds + 16384 + (wn * 64 + (lane & 15)) * 32 + pg * 8;

  const bf16* gA_0 = A  + (m0_0 + rA0 + rl) * (long)lda + scol;
  const bf16* gB_0 = Bt + (n0_0 + rB0 + rl) * (long)ldb + scol;
  const bf16* gA_1 = A  + (m0_1 + rA0 + rl) * (long)lda + scol;
  const bf16* gB_1 = Bt + (n0_1 + rB0 + rl) * (long)ldb + scol;

  stage_pro256(gA_0, gB_0, lda, ldb, lA, lB);
  asm volatile("s_waitcnt vmcnt(10)" ::: "memory");
  __builtin_amdgcn_s_barrier();

  const int r0 = wm * 128 + ((lane >> 4) << 2);
  const int c0 = wn * 64 + (lane & 15);

#pragma unroll 1
  for (int t = 0; t < 2; ++t) {
    const bf16* gA = (t == 0) ? gA_0 : gA_1;
    const bf16* gB = (t == 0) ? gB_0 : gB_1;
    const long m0 = (t == 0) ? m0_0 : m0_1;
    const long n0 = (t == 0) ? n0_0 : n0_1;
    floatx4 acc[8][4];
#pragma unroll
    for (int i = 0; i < 8; i++)
#pragma unroll
      for (int j = 0; j < 4; j++) acc[i][j] = (floatx4){0.f, 0.f, 0.f, 0.f};
    core256_loop(gA, gB, lda, ldb, K, fa0, fb0, lA, lB, acc);

    if (t == 0) stage_pro256(gA_1, gB_1, lda, ldb, lA, lB);

#pragma unroll
    for (int mf = 0; mf < 8; ++mf) {
#pragma unroll
      for (int i = 0; i < 4; ++i) {
        long r = m0 + r0 + mf * 16 + i;
        long bidx = r * (long)ldc + n0 + c0;
#pragma unroll
        for (int nf = 0; nf < 4; ++nf) {
          float v = acc[mf][nf][i];
          if constexpr (EPI == E_SILU) {
            ((bf16*)Cout)[bidx + nf * 16] = f2bf(v / (1.f + __expf(-v)));
          } else {
            ((bf16*)Cout)[bidx + nf * 16] = f2bf(v);
          }
        }
      }
    }
    if (t == 0) {
      asm volatile("s_waitcnt vmcnt(10)" ::: "memory");
      __builtin_amdgcn_s_barrier();
    }
  }
}

// ---------------- launch ----------------
extern "C" void kernel_launch(void* const* d_in, const int* in_sizes, int n_in,
                              void* d_out, int out_size, void* d_ws, size_t ws_size,
                              hipStream_t stream) {
  (void)in_sizes; (void)n_in; (void)out_size; (void)ws_size;
  const float* x        = (const float*)d_in[0];
  const float* ln0_g    = (const float*)d_in[1];
  const float* ln0_b    = (const float*)d_in[2];
  const float* pre_g    = (const float*)d_in[3];
  const float* pre_b    = (const float*)d_in[4];
  const float* post_g   = (const float*)d_in[5];
  const float* post_b   = (const float*)d_in[6];
  const float* tm_decay = (const float*)d_in[7];
  const float* tm_first = (const float*)d_in[8];
  const float* tm_mix_k = (const float*)d_in[9];
  const float* tm_mix_v = (const float*)d_in[10];
  const float* tm_mix_r = (const float*)d_in[11];
  const float* tm_Wk    = (const float*)d_in[12];
  const float* tm_Wv    = (const float*)d_in[13];
  const float* tm_Wr    = (const float*)d_in[14];
  const float* tm_Wo    = (const float*)d_in[15];
  const float* cm_mix_k = (const float*)d_in[16];
  const float* cm_mix_r = (const float*)d_in[17];
  const float* cm_Wk    = (const float*)d_in[18];
  const float* cm_Wv    = (const float*)d_in[19];
  const float* cm_Wr    = (const float*)d_in[20];

  char* ws = (char*)d_ws;
  // static layout (bytes); peak 238,026,752 (227 MiB)
  bf16*  WkT  = (bf16*)(ws + 0);          // [HU,H]
  bf16*  WvT  = (bf16*)(ws + 8388608);    // [HU,H]
  bf16*  WrT  = (bf16*)(ws + 16777216);   // [HU,H]
  bf16*  WoT  = (bf16*)(ws + 25165824);   // [H,HU]
  bf16*  cWkT = (bf16*)(ws + 33554432);   // [HU,H]
  bf16*  cWvT = (bf16*)(ws + 41943040);   // [H,HU]
  bf16*  cWrT = (bf16*)(ws + 50331648);   // [H,H]
  float* xres = (float*)(ws + 52428800);  // [M,H] f32
  bf16*  xk   = (bf16*)(ws + 85983232);   // [M,H]
  bf16*  xv   = (bf16*)(ws + 102760448);
  bf16*  xr   = (bf16*)(ws + 119537664);
  bf16*  Kc   = (bf16*)(ws + 136314880);  // [M,CHUNK]
  bf16*  Vc   = (bf16*)(ws + 169869312);  // [M,CHUNK]
  bf16*  SRc  = (bf16*)(ws + 203423744);  // [M,CHUNK], P written in place
  float* stK  = (float*)(ws + 236978176); // [NSEG,B,CHUNK] f32 (512 KiB)
  float* stKV = (float*)(ws + 237502464); // [NSEG,B,CHUNK] f32 (512 KiB)
  // CM-phase aliases (regions dead by then):
  bf16*  xk2  = (bf16*)(ws + 136314880);  // over Kc
  bf16*  xr2  = (bf16*)(ws + 153092096);  // over Kc (2nd half)
  bf16*  hbuf = (bf16*)(ws + 169869312);  // [M,HU] over Vc+SRc
  float* hv   = (float*)(ws + 85983232);  // [M,H] f32 over xk+xv

  dim3 blk(256);
  wconv_all<<<6400, blk, 0, stream>>>(tm_Wk, tm_Wv, tm_Wr, tm_Wo, cm_Wk, cm_Wv, cm_Wr,
                                      WkT, WvT, WrT, WoT, cWkT, cWvT, cWrT);

  ln_mix_tm<<<Mrows, blk, 0, stream>>>(x, ln0_g, ln0_b, pre_g, pre_b,
                                       tm_mix_k, tm_mix_v, tm_mix_r, xres, xk, xv, xr);

  const int scan_grid = NSEG * Bdim * (CHUNK / 128);  // 1024 blocks
  const int GM8 = Mrows / 256;                         // 32 (256-row tiles)
  const int GN8p = CHUNK / 256;                        // 8
  const int GNn = Hdim / 128;                          // 8 (gemm8n n-tiles)
  for (int ch = 0; ch < NCH; ch++) {
    const long woff = (long)ch * CHUNK;
    // persistent 3-tile K/V/R projection: 256 blocks, each does K,V,R at one swz position
    proj8p<<<GM8 * GN8p, dim3(512), 0, stream>>>(
        xk, xv, xr, WkT + woff * Hdim, WvT + woff * Hdim, WrT + woff * Hdim,
        Kc, Vc, SRc, GM8, GN8p);

    wkv_part<<<scan_grid, dim3(64), 0, stream>>>(
        Kc, Vc, stK, stKV, tm_decay + woff);
    wkv_emit<<<scan_grid, dim3(64), 0, stream>>>(
        Kc, Vc, SRc, SRc, stK, stKV, tm_decay + woff, tm_first + woff);

    // xres += P_ch @ Wo[ch*CHUNK:,:]  -> 256x128-tile one-barrier core, 256 blocks
    gemm8n<E_ADD1><<<GM8 * GNn, dim3(512), 0, stream>>>(
        SRc, WoT + woff, xres, xres, nullptr, CHUNK, HUdim, Hdim, CHUNK, GM8, GNn);
  }

  ln_mix_cm<<<Mrows, blk, 0, stream>>>(xres, post_g, post_b, cm_mix_k, cm_mix_r, xk2, xr2);

  // hbuf = silu(xk2 @ cWk): persistent 2-tile 256^2 core, 256 blocks x 2 tiles = 512 tiles
  gemm8p2<E_SILU><<<(GM8 * (HUdim/256)) / 2, dim3(512), 0, stream>>>(
      xk2, cWkT, hbuf, Hdim, Hdim, HUdim, Hdim, GM8, HUdim/256);

  // hv = hbuf @ cWv in ONE K=4096 launch (n128 core, 256 blocks = full fill)
  gemm8n<E_F32><<<GM8 * GNn, dim3(512), 0, stream>>>(
      hbuf, cWvT, hv, nullptr, nullptr, HUdim, HUdim, Hdim, HUdim, GM8, GNn);

  gemm8n<E_SIGADD2><<<GM8 * GNn, dim3(512), 0, stream>>>(
      xr2, cWrT, (float*)d_out, xres, hv, Hdim, Hdim, Hdim, Hdim, GM8, GNn);
}

// Round 8
// 873.789 us; speedup vs baseline: 1.2259x; 1.2259x over previous
//
#include <hip/hip_runtime.h>

#define Hdim  1024
#define Tdim  2048
#define Bdim  4
#define HUdim 4096
#define Mrows (Bdim*Tdim)   // 8192
#define CHUNK 2048          // HU processed in HUdim/CHUNK slices
#define NCH   (HUdim/CHUNK) // 2
#define NSEG  16            // T-segments for parallel scan
#define SEGL  (Tdim/NSEG)   // 128
#define SCHUNK 16

typedef __bf16 bf16;
typedef __bf16 bf16x2 __attribute__((ext_vector_type(2)));
typedef __bf16 bf16x4 __attribute__((ext_vector_type(4)));
typedef __bf16 bf16x8 __attribute__((ext_vector_type(8)));
typedef float  floatx4 __attribute__((ext_vector_type(4)));

__device__ __forceinline__ bf16 f2bf(float x) { return (bf16)x; }

// ---------------- fused weight transpose + f32->bf16 convert (all 7 weights) ----------------
__global__ __launch_bounds__(256) void wconv_all(
    const float* __restrict__ s0, const float* __restrict__ s1, const float* __restrict__ s2,
    const float* __restrict__ s3, const float* __restrict__ s4, const float* __restrict__ s5,
    const float* __restrict__ s6,
    bf16* d0, bf16* d1, bf16* d2, bf16* d3, bf16* d4, bf16* d5, bf16* d6) {
  __shared__ float tile[64][65];
  int bid = blockIdx.x;
  const float* src; bf16* dst; int K, N, local;
  if (bid < 1024)      { src = s0; dst = d0; K = Hdim;  N = HUdim; local = bid; }
  else if (bid < 2048) { src = s1; dst = d1; K = Hdim;  N = HUdim; local = bid - 1024; }
  else if (bid < 3072) { src = s2; dst = d2; K = Hdim;  N = HUdim; local = bid - 2048; }
  else if (bid < 4096) { src = s3; dst = d3; K = HUdim; N = Hdim;  local = bid - 3072; }
  else if (bid < 5120) { src = s4; dst = d4; K = Hdim;  N = HUdim; local = bid - 4096; }
  else if (bid < 6144) { src = s5; dst = d5; K = HUdim; N = Hdim;  local = bid - 5120; }
  else                 { src = s6; dst = d6; K = Hdim;  N = Hdim;  local = bid - 6144; }
  const int nt = N >> 6;
  const int n0 = (local % nt) * 64, k0 = (local / nt) * 64;
  const int tr = threadIdx.x >> 6;   // 0..3
  const int tc = threadIdx.x & 63;
#pragma unroll
  for (int j = 0; j < 16; j++) {
    int r = j * 4 + tr;
    tile[r][tc] = src[(size_t)(k0 + r) * N + n0 + tc];
  }
  __syncthreads();
#pragma unroll
  for (int j = 0; j < 16; j++) {
    int r = j * 4 + tr;
    dst[(size_t)(n0 + r) * K + k0 + tc] = f2bf(tile[tc][r]);
  }
}

// ---------------- block reduction helper (256 threads, 4 values) ----------------
__device__ __forceinline__ void block_reduce4(float v[4], float* sm) {
#pragma unroll
  for (int off = 32; off > 0; off >>= 1) {
#pragma unroll
    for (int i = 0; i < 4; i++) v[i] += __shfl_down(v[i], off, 64);
  }
  const int w = threadIdx.x >> 6;
  if ((threadIdx.x & 63) == 0) {
#pragma unroll
    for (int i = 0; i < 4; i++) sm[w * 4 + i] = v[i];
  }
  __syncthreads();
#pragma unroll
  for (int i = 0; i < 4; i++) v[i] = sm[i] + sm[4 + i] + sm[8 + i] + sm[12 + i];
  __syncthreads();
}

// ---------------- ln0 + pre-LN + shift + TM mixes ----------------
__global__ __launch_bounds__(256) void ln_mix_tm(
    const float* __restrict__ x,
    const float* __restrict__ g0, const float* __restrict__ b0,
    const float* __restrict__ g1, const float* __restrict__ b1,
    const float* __restrict__ mk, const float* __restrict__ mv, const float* __restrict__ mr,
    float* __restrict__ x0, bf16* __restrict__ xk, bf16* __restrict__ xv, bf16* __restrict__ xr) {
  __shared__ float sm[16];
  const int bid = blockIdx.x;
  const int t = bid & (Tdim - 1);
  const int tid = threadIdx.x;
  const bool havep = (t > 0);
  const float hp = havep ? 1.f : 0.f;
  const float* rowc = x + (size_t)bid * Hdim;
  const float* rowp = havep ? (rowc - Hdim) : rowc;  // always in-bounds

  float c[4], p[4];
#pragma unroll
  for (int j = 0; j < 4; j++) c[j] = rowc[tid * 4 + j];
#pragma unroll
  for (int j = 0; j < 4; j++) p[j] = rowp[tid * 4 + j] * hp;

  float red[4] = {0.f, 0.f, 0.f, 0.f};
#pragma unroll
  for (int j = 0; j < 4; j++) { red[0] += c[j]; red[1] += c[j]*c[j]; red[2] += p[j]; red[3] += p[j]*p[j]; }
  block_reduce4(red, sm);
  const float inv = 1.f / Hdim;
  float mc = red[0]*inv, vc = red[1]*inv - mc*mc;
  float mp = red[2]*inv, vp = red[3]*inv - mp*mp;
  float sc = rsqrtf(vc + 1e-5f), sp = rsqrtf(vp + 1e-5f);

  float yc[4], yp[4];
#pragma unroll
  for (int j = 0; j < 4; j++) {
    int i = tid * 4 + j;
    yc[j] = (c[j] - mc) * sc * g0[i] + b0[i];
    yp[j] = ((p[j] - mp) * sp * g0[i] + b0[i]) * hp;
    x0[(size_t)bid * Hdim + i] = yc[j];
  }

  float r2[4] = {0.f, 0.f, 0.f, 0.f};
#pragma unroll
  for (int j = 0; j < 4; j++) { r2[0] += yc[j]; r2[1] += yc[j]*yc[j]; r2[2] += yp[j]; r2[3] += yp[j]*yp[j]; }
  block_reduce4(r2, sm);
  float mc2 = r2[0]*inv, vc2 = r2[1]*inv - mc2*mc2;
  float mp2 = r2[2]*inv, vp2 = r2[3]*inv - mp2*mp2;
  float sc2 = rsqrtf(vc2 + 1e-5f), sp2 = rsqrtf(vp2 + 1e-5f);

#pragma unroll
  for (int j = 0; j < 4; j++) {
    int i = tid * 4 + j;
    float xnc = (yc[j] - mc2) * sc2 * g1[i] + b1[i];
    float xnp = ((yp[j] - mp2) * sp2 * g1[i] + b1[i]) * hp;
    size_t o = (size_t)bid * Hdim + i;
    float a;
    a = mk[i]; xk[o] = f2bf(xnc * a + xnp * (1.f - a));
    a = mv[i]; xv[o] = f2bf(xnc * a + xnp * (1.f - a));
    a = mr[i]; xr[o] = f2bf(xnc * a + xnp * (1.f - a));
  }
}

// ---------------- post-LN + shift + CM mixes ----------------
__global__ __launch_bounds__(256) void ln_mix_cm(
    const float* __restrict__ xin,
    const float* __restrict__ g, const float* __restrict__ bb,
    const float* __restrict__ mk, const float* __restrict__ mr,
    bf16* __restrict__ xk, bf16* __restrict__ xr) {
  __shared__ float sm[16];
  const int bid = blockIdx.x;
  const int t = bid & (Tdim - 1);
  const int tid = threadIdx.x;
  const bool havep = (t > 0);
  const float hp = havep ? 1.f : 0.f;
  const float* rowc = xin + (size_t)bid * Hdim;
  const float* rowp = havep ? (rowc - Hdim) : rowc;

  float c[4], p[4];
#pragma unroll
  for (int j = 0; j < 4; j++) c[j] = rowc[tid * 4 + j];
#pragma unroll
  for (int j = 0; j < 4; j++) p[j] = rowp[tid * 4 + j] * hp;

  float red[4] = {0.f, 0.f, 0.f, 0.f};
#pragma unroll
  for (int j = 0; j < 4; j++) { red[0] += c[j]; red[1] += c[j]*c[j]; red[2] += p[j]; red[3] += p[j]*p[j]; }
  block_reduce4(red, sm);
  const float inv = 1.f / Hdim;
  float mc = red[0]*inv, vc = red[1]*inv - mc*mc;
  float mp = red[2]*inv, vp = red[3]*inv - mp*mp;
  float sc = rsqrtf(vc + 1e-5f), sp = rsqrtf(vp + 1e-5f);

#pragma unroll
  for (int j = 0; j < 4; j++) {
    int i = tid * 4 + j;
    float xnc = (c[j] - mc) * sc * g[i] + bb[i];
    float xnp = ((p[j] - mp) * sp * g[i] + bb[i]) * hp;
    size_t o = (size_t)bid * Hdim + i;
    float a;
    a = mk[i]; xk[o] = f2bf(xnc * a + xnp * (1.f - a));
    a = mr[i]; xr[o] = f2bf(xnc * a + xnp * (1.f - a));
  }
}

// ---------------- WKV parallel scan, 4 channels/thread, bf16x4 (8B/lane) loads ----------------
// grid = NSEG * Bdim * (CHUNK/256) = 512 blocks of 64 threads. Per-channel arithmetic
// order identical to the bf16x2 version -> bitwise-same results.
__global__ __launch_bounds__(64) void wkv_part(
    const bf16* __restrict__ Kb, const bf16* __restrict__ Vb,
    float* __restrict__ stK, float* __restrict__ stKV,
    const float* __restrict__ tdec) {
  const int seg = blockIdx.x & (NSEG - 1);
  const int rest = blockIdx.x >> 4;       // b*8 + g
  const int b = rest >> 3, g = rest & 7;
  const int c = (g << 8) + (threadIdx.x << 2);
  float d[4];
#pragma unroll
  for (int i = 0; i < 4; i++) d[i] = __expf(-__expf(tdec[c + i]));
  size_t base = ((size_t)b * Tdim + (size_t)seg * SEGL) * CHUNK + c;
  float sk[4] = {0.f, 0.f, 0.f, 0.f}, skv[4] = {0.f, 0.f, 0.f, 0.f};
  for (int t0 = 0; t0 < SEGL; t0 += SCHUNK) {
    bf16x4 kk[SCHUNK], vv[SCHUNK];
#pragma unroll
    for (int j = 0; j < SCHUNK; j++) {
      size_t idx = base + (size_t)(t0 + j) * CHUNK;
      kk[j] = *(const bf16x4*)(Kb + idx);
      vv[j] = *(const bf16x4*)(Vb + idx);
    }
#pragma unroll
    for (int j = 0; j < SCHUNK; j++)
#pragma unroll
      for (int i = 0; i < 4; i++) {
        float k = (float)kk[j][i], v = (float)vv[j][i];
        sk[i]  = fmaf(d[i], sk[i], k);
        skv[i] = fmaf(d[i], skv[i], k * v);
      }
  }
  size_t so = ((size_t)seg * Bdim + b) * CHUNK + c;
  *(floatx4*)(stK + so)  = (floatx4){sk[0], sk[1], sk[2], sk[3]};
  *(floatx4*)(stKV + so) = (floatx4){skv[0], skv[1], skv[2], skv[3]};
}

__global__ __launch_bounds__(64) void wkv_emit(
    const bf16* __restrict__ Kb, const bf16* __restrict__ Vb,
    const bf16* SRb, bf16* Pb,   // SRb/Pb alias: per-element read-before-write
    const float* __restrict__ stK, const float* __restrict__ stKV,
    const float* __restrict__ tdec, const float* __restrict__ tfst) {
  const int seg = blockIdx.x & (NSEG - 1);
  const int rest = blockIdx.x >> 4;
  const int b = rest >> 3, g = rest & 7;
  const int c = (g << 8) + (threadIdx.x << 2);
  float d[4], df[4], f[4];
#pragma unroll
  for (int i = 0; i < 4; i++) {
    float ed = __expf(tdec[c + i]);
    d[i]  = __expf(-ed);
    df[i] = __expf(-ed * (float)SEGL);
    f[i]  = __expf(tfst[c + i]);
  }
  float sk[4] = {0.f, 0.f, 0.f, 0.f}, skv[4] = {0.f, 0.f, 0.f, 0.f};
  for (int j = 0; j < seg; j++) {
    size_t so = ((size_t)j * Bdim + b) * CHUNK + c;
    floatx4 pk  = *(const floatx4*)(stK + so);
    floatx4 pkv = *(const floatx4*)(stKV + so);
#pragma unroll
    for (int i = 0; i < 4; i++) {
      sk[i]  = fmaf(df[i], sk[i],  pk[i]);
      skv[i] = fmaf(df[i], skv[i], pkv[i]);
    }
  }

  size_t base = ((size_t)b * Tdim + (size_t)seg * SEGL) * CHUNK + c;
  for (int t0 = 0; t0 < SEGL; t0 += SCHUNK) {
    bf16x4 kk[SCHUNK], vv[SCHUNK], rr[SCHUNK];
#pragma unroll
    for (int j = 0; j < SCHUNK; j++) {
      size_t idx = base + (size_t)(t0 + j) * CHUNK;
      kk[j] = *(const bf16x4*)(Kb + idx);
      vv[j] = *(const bf16x4*)(Vb + idx);
      rr[j] = *(const bf16x4*)(SRb + idx);
    }
#pragma unroll
    for (int j = 0; j < SCHUNK; j++) {
      size_t idx = base + (size_t)(t0 + j) * CHUNK;
      bf16x4 out;
#pragma unroll
      for (int i = 0; i < 4; i++) {
        float k = (float)kk[j][i], v = (float)vv[j][i];
        float kv = k * v;
        float wk  = fmaf(f[i], k, sk[i]) + 1e-8f;
        float wkv = fmaf(f[i], kv, skv[i]);
        out[i] = f2bf((float)rr[j][i] * wkv * __builtin_amdgcn_rcpf(wk));
        sk[i]  = fmaf(d[i], sk[i], k);
        skv[i] = fmaf(d[i], skv[i], kv);
      }
      *(bf16x4*)(Pb + idx) = out;
    }
  }
}

// ---------------- shared helpers ----------------
__device__ __forceinline__ void gld_lds(const bf16* g, bf16* l) {
  __builtin_amdgcn_global_load_lds(
      (const __attribute__((address_space(1))) void*)(g),
      (__attribute__((address_space(3))) void*)(l),
      16, 0, 0);
}

// XCD-aware swizzle: xcd=s%8 owns m-band; n in groups of 2, m fastest.
__device__ __forceinline__ void swz(int s, int gm, int& m_t, int& n_t) {
  const int mpx  = gm >> 3;        // gm % 8 == 0 at all call sites
  const int xcd  = s & 7;
  const int ss   = s >> 3;
  const int pass = mpx << 1;
  const int ng   = ss / pass;
  const int rem  = ss - ng * pass;
  m_t = xcd * mpx + (rem >> 1);
  n_t = (ng << 1) + (rem & 1);
}

enum { E_EXP = 0, E_BF16 = 1, E_SIG = 2, E_ADD1 = 3, E_SILU = 4, E_F32 = 5, E_SIGADD2 = 6 };

template <int EPI>
__device__ __forceinline__ void epilogue(
    floatx4 acc[4][4], void* Cout, const void* aux1, const void* aux2,
    long m0, long n0, int ldc, int lane, int wm, int wn) {
  const int r0 = wm * 64 + ((lane >> 4) << 2);
  const int c0 = wn * 64 + (lane & 15);
#pragma unroll
  for (int mt = 0; mt < 4; mt++) {
#pragma unroll
    for (int i = 0; i < 4; i++) {
      long r = m0 + r0 + mt * 16 + i;
      long bidx = r * (long)ldc + n0 + c0;
#pragma unroll
      for (int nt = 0; nt < 4; nt++) {
        long idx = bidx + nt * 16;
        float v = acc[mt][nt][i];
        if constexpr (EPI == E_EXP) {
          ((bf16*)Cout)[idx] = f2bf(__expf(fminf(v, 60.f)));
        } else if constexpr (EPI == E_BF16) {
          ((bf16*)Cout)[idx] = f2bf(v);
        } else if constexpr (EPI == E_SIG) {
          ((bf16*)Cout)[idx] = f2bf(1.f / (1.f + __expf(-v)));
        } else if constexpr (EPI == E_ADD1) {
          float prev = ((const float*)aux1)[idx];   // may alias Cout (same idx)
          ((float*)Cout)[idx] = v + prev;
        } else if constexpr (EPI == E_SILU) {
          ((bf16*)Cout)[idx] = f2bf(v / (1.f + __expf(-v)));
        } else if constexpr (EPI == E_F32) {
          ((float*)Cout)[idx] = v;
        } else {  // E_SIGADD2
          float a1 = ((const float*)aux1)[idx];
          float a2 = ((const float*)aux2)[idx];
          ((float*)Cout)[idx] = a1 + 1.f / (1.f + __expf(-v)) + a2;
        }
      }
    }
  }
}

// =====================================================================================
// 256x128-tile GEMM core, BK=64, TRIPLE-buffered LDS (3 x 48 KiB = 144 KiB), 8 waves
// (4M x 2N, 64x64 output each), ONE barrier + ONE counted vmcnt per K-iter.
// (R4-measured version.)
// =====================================================================================
__device__ __forceinline__ void mm_core_n128(
    const bf16* __restrict__ A, const bf16* __restrict__ Bt,
    int lda, int ldb, int K, long m0, long n0,
    int wv, int lane, bf16* Lds, floatx4 acc[4][4]) {
  const int rl  = lane >> 2;
  const int scol = (((lane & 3) - ((lane >> 3) & 3)) & 3) * 8;  // phase-swizzled k-slot
  const bf16* gA = A + (m0 + wv * 16 + rl) * (long)lda + scol;
  const bf16* gB = Bt + (n0 + wv * 16 + rl) * (long)ldb + scol;
  bf16* lA = Lds + wv * 512;            // + buf*16384 + h*4096; second k-panel +8192
  bf16* lB = Lds + 49152 + wv * 512;    // + buf*8192;           second k-panel +4096

  const int wm = wv >> 1, wn = wv & 1;
  const int pg = ((lane >> 4) + ((lane >> 1) & 3)) & 3;
  const bf16* fa0 = Lds + (wm * 64 + (lane & 15)) * 32 + pg * 8;
  const bf16* fb0 = Lds + 49152 + (wn * 64 + (lane & 15)) * 32 + pg * 8;

#define STGA_N(buf, h, kt) do { \
    const bf16* _s = gA + (long)(h) * 128 * lda + (long)(kt) * 64; \
    bf16* _d = lA + (buf) * 16384 + (h) * 4096; \
    gld_lds(_s, _d); gld_lds(_s + 32, _d + 8192); } while (0)
#define STGB_N(buf, kt) do { \
    const bf16* _s = gB + (long)(kt) * 64; \
    bf16* _d = lB + (buf) * 8192; \
    gld_lds(_s, _d); gld_lds(_s + 32, _d + 4096); } while (0)

  STGA_N(0, 0, 0); STGA_N(0, 1, 0); STGB_N(0, 0);
  STGA_N(1, 0, 1); STGA_N(1, 1, 1); STGB_N(1, 1);
  asm volatile("s_waitcnt vmcnt(6)" ::: "memory");
  __builtin_amdgcn_s_barrier();

  const int niter = K >> 6;            // K % 64 == 0
  int p = 0;
  for (int it = 0; it < niter; ++it) {
    const int q = (p >= 1) ? p - 1 : p + 2;      // (p+2)%3
    const bool dostage = (it <= niter - 3);
    const bf16* fa = fa0 + p * 16384;
    const bf16* fb = fb0 + p * 8192;

    // ---- kh = 0 ----
    bf16x8 a0[4], b0v[4];
#pragma unroll
    for (int i = 0; i < 4; ++i) {
      a0[i]  = *(const bf16x8*)(fa + i * 512);
      b0v[i] = *(const bf16x8*)(fb + i * 512);
    }
    __builtin_amdgcn_sched_barrier(0);
    if (dostage) { STGA_N(q, 0, it + 2); STGA_N(q, 1, it + 2); }
    asm volatile("s_waitcnt lgkmcnt(0)" ::: "memory");
    __builtin_amdgcn_s_setprio(1);
#pragma unroll
    for (int mf = 0; mf < 4; ++mf)
#pragma unroll
      for (int nf = 0; nf < 4; ++nf)
        acc[mf][nf] = __builtin_amdgcn_mfma_f32_16x16x32_bf16(a0[mf], b0v[nf], acc[mf][nf], 0, 0, 0);
    __builtin_amdgcn_s_setprio(0);

    // ---- kh = 1 ----
    bf16x8 a1[4], b1v[4];
#pragma unroll
    for (int i = 0; i < 4; ++i) {
      a1[i]  = *(const bf16x8*)(fa + 8192 + i * 512);
      b1v[i] = *(const bf16x8*)(fb + 4096 + i * 512);
    }
    __builtin_amdgcn_sched_barrier(0);
    if (dostage) STGB_N(q, it + 2);
    asm volatile("s_waitcnt lgkmcnt(0)" ::: "memory");
    __builtin_amdgcn_s_setprio(1);
#pragma unroll
    for (int mf = 0; mf < 4; ++mf)
#pragma unroll
      for (int nf = 0; nf < 4; ++nf)
        acc[mf][nf] = __builtin_amdgcn_mfma_f32_16x16x32_bf16(a1[mf], b1v[nf], acc[mf][nf], 0, 0, 0);
    __builtin_amdgcn_s_setprio(0);

    if (it < niter - 1) {
      if (dostage) asm volatile("s_waitcnt vmcnt(6)" ::: "memory");
      else         asm volatile("s_waitcnt vmcnt(0)" ::: "memory");
      __builtin_amdgcn_s_barrier();
    }
    p = (p == 2) ? 0 : p + 1;
  }
#undef STGA_N
#undef STGB_N
}

// 256x128-tile kernel: grid = (M/256)*(N/128) blocks.
template <int EPI>
__global__ __launch_bounds__(512, 2) void gemm8n(
    const bf16* __restrict__ A, const bf16* __restrict__ Bt,
    void* Cout, const void* aux1, const void* aux2,
    int lda, int ldb, int ldc, int K, int gm, int gn) {
  __shared__ __align__(16) bf16 Lds[73728];   // 144 KiB
  const int tid = threadIdx.x;
  const int lane = tid & 63;
  const int wv = tid >> 6;
  int m_t, n_t;
  swz(blockIdx.x, gm, m_t, n_t);
  const long m0 = (long)m_t * 256, n0 = (long)n_t * 128;
  floatx4 acc[4][4];
#pragma unroll
  for (int i = 0; i < 4; i++)
#pragma unroll
    for (int j = 0; j < 4; j++) acc[i][j] = (floatx4){0.f, 0.f, 0.f, 0.f};
  mm_core_n128(A, Bt, lda, ldb, K, m0, n0, wv, lane, Lds, acc);
  const int wm = wv >> 1, wn = wv & 1;   // 4M x 2N waves, 64x64 each
  epilogue<EPI>(acc, Cout, aux1, aux2, m0, n0, ldc, lane, wm, wn);
}

// =====================================================================================
// 8-phase 256x256 GEMM core (zigzag quadrant order) — R2/R4-measured version.
// =====================================================================================
__device__ __forceinline__ void mm_core256(
    const bf16* __restrict__ A, const bf16* __restrict__ Bt,
    int lda, int ldb, int K, long m0, long n0,
    int wv, int lane, bf16* Lds, floatx4 acc[8][4]) {
  const int wm = wv >> 2, wn = wv & 3;
  const int rA0 = wm * 128 + (wv & 3) * 16;
  const int rB0 = (wv >> 1) * 64 + (wv & 1) * 16;
  const int rl  = lane >> 2;
  const int scol = (((lane & 3) - ((lane >> 3) & 3)) & 3) * 8;
  const bf16* gA = A + (m0 + rA0 + rl) * (long)lda + scol;
  const bf16* gB = Bt + (n0 + rB0 + rl) * (long)ldb + scol;
  bf16* lA = Lds + rA0 * 32;
  bf16* lB = Lds + 16384 + rB0 * 32;

  const int pg = ((lane >> 4) + ((lane >> 1) & 3)) & 3;
  const bf16* fa0 = Lds + (wm * 128 + (lane & 15)) * 32 + pg * 8;
  const bf16* fb0 = Lds + 16384 + (wn * 64 + (lane & 15)) * 32 + pg * 8;

#define STGA8(buf, h, kt) do { \
    const bf16* _s = gA + (long)(h) * 64 * lda + (kt) * 64; \
    bf16* _d = lA + (buf) * 32768 + (h) * 2048; \
    gld_lds(_s, _d); gld_lds(_s + 32, _d + 8192); } while (0)
#define STGB8(buf, h, kt) do { \
    const bf16* _s = gB + (long)(h) * 32 * ldb + (kt) * 64; \
    bf16* _d = lB + (buf) * 32768 + (h) * 1024; \
    gld_lds(_s, _d); gld_lds(_s + 32, _d + 8192); } while (0)

  STGA8(0, 0, 0); STGB8(0, 0, 0); STGB8(0, 1, 0); STGA8(0, 1, 0);
  STGA8(1, 0, 1); STGB8(1, 0, 1); STGB8(1, 1, 1);
  asm volatile("s_waitcnt vmcnt(10)" ::: "memory");
  __builtin_amdgcn_s_barrier();

  const int niter = K >> 7;            // K % 128 == 0
  bf16x8 a[4][2];
  bf16x8 b[2][2][2];
  for (int it = 0; it < niter; ++it) {
    const int kt0 = it << 1;
    const bool notlast = (it != niter - 1);
#pragma unroll
    for (int ph = 0; ph < 8; ++ph) {
      const int q   = ph & 3;
      const int buf = ph >> 2;
      const int mq  = q >> 1;
      const int nq  = (q >> 1) ^ (q & 1);
      const bf16* fa = fa0 + buf * 32768 + mq * 2048;
      const bf16* fb = fb0 + buf * 32768 + nq * 1024;
      if (q == 0) {
#pragma unroll
        for (int mf = 0; mf < 4; ++mf) {
          a[mf][0] = *(const bf16x8*)(fa + mf * 512);
          a[mf][1] = *(const bf16x8*)(fa + mf * 512 + 8192);
        }
#pragma unroll
        for (int nf = 0; nf < 2; ++nf) {
          b[0][nf][0] = *(const bf16x8*)(fb + nf * 512);
          b[0][nf][1] = *(const bf16x8*)(fb + nf * 512 + 8192);
        }
      } else if (q == 1) {
#pragma unroll
        for (int nf = 0; nf < 2; ++nf) {
          b[1][nf][0] = *(const bf16x8*)(fb + nf * 512);
          b[1][nf][1] = *(const bf16x8*)(fb + nf * 512 + 8192);
        }
      } else if (q == 2) {
#pragma unroll
        for (int mf = 0; mf < 4; ++mf) {
          a[mf][0] = *(const bf16x8*)(fa + mf * 512);
          a[mf][1] = *(const bf16x8*)(fa + mf * 512 + 8192);
        }
      }
      __builtin_amdgcn_sched_barrier(0);
      if (ph == 0)            STGA8(1, 1, kt0 + 1);
      else if (notlast) {
        if (ph == 1)      STGA8(0, 0, kt0 + 2);
        else if (ph == 2) STGB8(0, 0, kt0 + 2);
        else if (ph == 3) STGB8(0, 1, kt0 + 2);
        else if (ph == 4) STGA8(0, 1, kt0 + 2);
        else if (ph == 5) STGA8(1, 0, kt0 + 3);
        else if (ph == 6) STGB8(1, 0, kt0 + 3);
        else              STGB8(1, 1, kt0 + 3);
      }
      if (notlast) {
        if (ph == 0 || ph == 1 || ph == 4 || ph == 5)
          asm volatile("s_waitcnt vmcnt(10)" ::: "memory");
        else if (ph == 3 || ph == 7)
          asm volatile("s_waitcnt vmcnt(12)" ::: "memory");
      } else {
        if (ph == 0)      asm volatile("s_waitcnt vmcnt(10)" ::: "memory");
        else if (ph == 1) asm volatile("s_waitcnt vmcnt(0)" ::: "memory");
      }
      if (q != 3) {
        __builtin_amdgcn_s_barrier();
        asm volatile("s_waitcnt lgkmcnt(0)" ::: "memory");
      }
      __builtin_amdgcn_s_setprio(1);
#pragma unroll
      for (int mf = 0; mf < 4; ++mf)
#pragma unroll
        for (int nf = 0; nf < 2; ++nf) {
          acc[mq*4+mf][nq*2+nf] = __builtin_amdgcn_mfma_f32_16x16x32_bf16(
              a[mf][0], b[nq][nf][0], acc[mq*4+mf][nq*2+nf], 0, 0, 0);
          acc[mq*4+mf][nq*2+nf] = __builtin_amdgcn_mfma_f32_16x16x32_bf16(
              a[mf][1], b[nq][nf][1], acc[mq*4+mf][nq*2+nf], 0, 0, 0);
        }
      __builtin_amdgcn_s_setprio(0);
      __builtin_amdgcn_s_barrier();
    }
  }
#undef STGA8
#undef STGB8
}

template <int EPI>
__global__ __launch_bounds__(512, 2) void gemm8(
    const bf16* __restrict__ A, const bf16* __restrict__ Bt,
    void* Cout, const void* aux1, const void* aux2,
    int lda, int ldb, int ldc, int K, int gm, int gn) {
  __shared__ __align__(16) bf16 Lds[65536];   // 128 KiB
  const int tid = threadIdx.x;
  const int lane = tid & 63;
  const int wv = tid >> 6;
  int m_t, n_t;
  swz(blockIdx.x, gm, m_t, n_t);
  const long m0 = (long)m_t * 256, n0 = (long)n_t * 256;
  floatx4 acc[8][4];
#pragma unroll
  for (int i = 0; i < 8; i++)
#pragma unroll
    for (int j = 0; j < 4; j++) acc[i][j] = (floatx4){0.f, 0.f, 0.f, 0.f};
  mm_core256(A, Bt, lda, ldb, K, m0, n0, wv, lane, Lds, acc);

  const int wm = wv >> 2, wn = wv & 3;
  const int r0 = wm * 128 + ((lane >> 4) << 2);
  const int c0 = wn * 64 + (lane & 15);
#pragma unroll
  for (int mf = 0; mf < 8; ++mf) {
#pragma unroll
    for (int i = 0; i < 4; ++i) {
      long r = m0 + r0 + mf * 16 + i;
      long bidx = r * (long)ldc + n0 + c0;
#pragma unroll
      for (int nf = 0; nf < 4; ++nf) {
        long idx = bidx + nf * 16;
        float v = acc[mf][nf][i];
        if constexpr (EPI == E_SILU) {
          ((bf16*)Cout)[idx] = f2bf(v / (1.f + __expf(-v)));
        } else if constexpr (EPI == E_BF16) {
          ((bf16*)Cout)[idx] = f2bf(v);
        } else if constexpr (EPI == E_F32) {
          ((float*)Cout)[idx] = v;
        } else if constexpr (EPI == E_ADD1) {
          float prev = ((const float*)aux1)[idx];
          ((float*)Cout)[idx] = v + prev;
        }
      }
    }
  }
}

// ---------------- fused K/V/R projection on the 8-phase core ----------------
__global__ __launch_bounds__(512, 2) void proj8(
    const bf16* __restrict__ xk, const bf16* __restrict__ xv, const bf16* __restrict__ xr,
    const bf16* __restrict__ Wk, const bf16* __restrict__ Wv, const bf16* __restrict__ Wr,
    bf16* Kc, bf16* Vc, bf16* SRc, int gm, int gn) {
  __shared__ __align__(16) bf16 Lds[65536];   // 128 KiB
  const int per = gm * gn;
  const int sub = blockIdx.x / per;           // 0:K 1:V 2:R
  const int s   = blockIdx.x - sub * per;
  const int tid = threadIdx.x;
  const int lane = tid & 63;
  const int wv = tid >> 6;
  int m_t, n_t;
  swz(s, gm, m_t, n_t);
  const long m0 = (long)m_t * 256, n0 = (long)n_t * 256;

  const bf16* A  = (sub == 0) ? xk : (sub == 1) ? xv : xr;
  const bf16* Bt = (sub == 0) ? Wk : (sub == 1) ? Wv : Wr;
  bf16*       C  = (sub == 0) ? Kc : (sub == 1) ? Vc : SRc;

  floatx4 acc[8][4];
#pragma unroll
  for (int i = 0; i < 8; i++)
#pragma unroll
    for (int j = 0; j < 4; j++) acc[i][j] = (floatx4){0.f, 0.f, 0.f, 0.f};
  mm_core256(A, Bt, Hdim, Hdim, Hdim, m0, n0, wv, lane, Lds, acc);

  const int wm = wv >> 2, wn = wv & 3;
  const int r0 = wm * 128 + ((lane >> 4) << 2);
  const int c0 = wn * 64 + (lane & 15);
#pragma unroll
  for (int mf = 0; mf < 8; ++mf) {
#pragma unroll
    for (int i = 0; i < 4; ++i) {
      long r = m0 + r0 + mf * 16 + i;
      long bidx = r * (long)CHUNK + n0 + c0;
#pragma unroll
      for (int nf = 0; nf < 4; ++nf) {
        long idx = bidx + nf * 16;
        float v = acc[mf][nf][i];
        float o;
        if (sub == 0)      o = __expf(fminf(v, 60.f));
        else if (sub == 1) o = v;
        else               o = 1.f / (1.f + __expf(-v));
        C[idx] = f2bf(o);
      }
    }
  }
}

// ---------------- launch ----------------
extern "C" void kernel_launch(void* const* d_in, const int* in_sizes, int n_in,
                              void* d_out, int out_size, void* d_ws, size_t ws_size,
                              hipStream_t stream) {
  (void)in_sizes; (void)n_in; (void)out_size; (void)ws_size;
  const float* x        = (const float*)d_in[0];
  const float* ln0_g    = (const float*)d_in[1];
  const float* ln0_b    = (const float*)d_in[2];
  const float* pre_g    = (const float*)d_in[3];
  const float* pre_b    = (const float*)d_in[4];
  const float* post_g   = (const float*)d_in[5];
  const float* post_b   = (const float*)d_in[6];
  const float* tm_decay = (const float*)d_in[7];
  const float* tm_first = (const float*)d_in[8];
  const float* tm_mix_k = (const float*)d_in[9];
  const float* tm_mix_v = (const float*)d_in[10];
  const float* tm_mix_r = (const float*)d_in[11];
  const float* tm_Wk    = (const float*)d_in[12];
  const float* tm_Wv    = (const float*)d_in[13];
  const float* tm_Wr    = (const float*)d_in[14];
  const float* tm_Wo    = (const float*)d_in[15];
  const float* cm_mix_k = (const float*)d_in[16];
  const float* cm_mix_r = (const float*)d_in[17];
  const float* cm_Wk    = (const float*)d_in[18];
  const float* cm_Wv    = (const float*)d_in[19];
  const float* cm_Wr    = (const float*)d_in[20];

  char* ws = (char*)d_ws;
  // static layout (bytes); peak 238,026,752 (227 MiB)
  bf16*  WkT  = (bf16*)(ws + 0);          // [HU,H]
  bf16*  WvT  = (bf16*)(ws + 8388608);    // [HU,H]
  bf16*  WrT  = (bf16*)(ws + 16777216);   // [HU,H]
  bf16*  WoT  = (bf16*)(ws + 25165824);   // [H,HU]
  bf16*  cWkT = (bf16*)(ws + 33554432);   // [HU,H]
  bf16*  cWvT = (bf16*)(ws + 41943040);   // [H,HU]
  bf16*  cWrT = (bf16*)(ws + 50331648);   // [H,H]
  float* xres = (float*)(ws + 52428800);  // [M,H] f32
  bf16*  xk   = (bf16*)(ws + 85983232);   // [M,H]
  bf16*  xv   = (bf16*)(ws + 102760448);
  bf16*  xr   = (bf16*)(ws + 119537664);
  bf16*  Kc   = (bf16*)(ws + 136314880);  // [M,CHUNK]
  bf16*  Vc   = (bf16*)(ws + 169869312);  // [M,CHUNK]
  bf16*  SRc  = (bf16*)(ws + 203423744);  // [M,CHUNK], P written in place
  float* stK  = (float*)(ws + 236978176); // [NSEG,B,CHUNK] f32 (512 KiB)
  float* stKV = (float*)(ws + 237502464); // [NSEG,B,CHUNK] f32 (512 KiB)
  // CM-phase aliases (regions dead by then):
  bf16*  xk2  = (bf16*)(ws + 136314880);  // over Kc
  bf16*  xr2  = (bf16*)(ws + 153092096);  // over Kc (2nd half)
  bf16*  hbuf = (bf16*)(ws + 169869312);  // [M,HU] over Vc+SRc
  float* hv   = (float*)(ws + 85983232);  // [M,H] f32 over xk+xv

  dim3 blk(256);
  wconv_all<<<6400, blk, 0, stream>>>(tm_Wk, tm_Wv, tm_Wr, tm_Wo, cm_Wk, cm_Wv, cm_Wr,
                                      WkT, WvT, WrT, WoT, cWkT, cWvT, cWrT);

  ln_mix_tm<<<Mrows, blk, 0, stream>>>(x, ln0_g, ln0_b, pre_g, pre_b,
                                       tm_mix_k, tm_mix_v, tm_mix_r, xres, xk, xv, xr);

  const int scan_grid = NSEG * Bdim * (CHUNK / 256);  // 512 blocks (4 ch/thread)
  const int GM8 = Mrows / 256;                         // 32 (256-row tiles)
  const int GN8p = CHUNK / 256;                        // 8
  const int GNn = Hdim / 128;                          // 8 (gemm8n n-tiles)
  for (int ch = 0; ch < NCH; ch++) {
    const long woff = (long)ch * CHUNK;
    // 3 fused GEMMs on the 8-phase 256^2 core: 768 blocks = 3 full waves of 256 CUs
    proj8<<<3 * GM8 * GN8p, dim3(512), 0, stream>>>(
        xk, xv, xr, WkT + woff * Hdim, WvT + woff * Hdim, WrT + woff * Hdim,
        Kc, Vc, SRc, GM8, GN8p);

    wkv_part<<<scan_grid, dim3(64), 0, stream>>>(
        Kc, Vc, stK, stKV, tm_decay + woff);
    wkv_emit<<<scan_grid, dim3(64), 0, stream>>>(
        Kc, Vc, SRc, SRc, stK, stKV, tm_decay + woff, tm_first + woff);

    // xres += P_ch @ Wo[ch*CHUNK:,:]  -> 256x128-tile one-barrier core, 256 blocks
    gemm8n<E_ADD1><<<GM8 * GNn, dim3(512), 0, stream>>>(
        SRc, WoT + woff, xres, xres, nullptr, CHUNK, HUdim, Hdim, CHUNK, GM8, GNn);
  }

  ln_mix_cm<<<Mrows, blk, 0, stream>>>(xres, post_g, post_b, cm_mix_k, cm_mix_r, xk2, xr2);

  // hbuf = silu(xk2 @ cWk) over full HU on the 8-phase core: 512 blocks
  gemm8<E_SILU><<<GM8 * (HUdim/256), dim3(512), 0, stream>>>(
      xk2, cWkT, hbuf, nullptr, nullptr, Hdim, Hdim, HUdim, Hdim, GM8, HUdim/256);

  // hv = hbuf @ cWv in ONE K=4096 launch (removes split + hv round-trip)
  gemm8n<E_F32><<<GM8 * GNn, dim3(512), 0, stream>>>(
      hbuf, cWvT, hv, nullptr, nullptr, HUdim, HUdim, Hdim, HUdim, GM8, GNn);

  gemm8n<E_SIGADD2><<<GM8 * GNn, dim3(512), 0, stream>>>(
      xr2, cWrT, (float*)d_out, xres, hv, Hdim, Hdim, Hdim, Hdim, GM8, GNn);
}

// Round 9
// 840.753 us; speedup vs baseline: 1.2741x; 1.0393x over previous
//
#include <hip/hip_runtime.h>

#define Hdim  1024
#define Tdim  2048
#define Bdim  4
#define HUdim 4096
#define Mrows (Bdim*Tdim)   // 8192
#define CHUNK 2048          // HU processed in HUdim/CHUNK slices
#define NCH   (HUdim/CHUNK) // 2
#define NSEG  16            // T-segments for parallel scan
#define SEGL  (Tdim/NSEG)   // 128
#define SCHUNK 16

typedef __bf16 bf16;
typedef __bf16 bf16x2 __attribute__((ext_vector_type(2)));
typedef __bf16 bf16x8 __attribute__((ext_vector_type(8)));
typedef float  floatx4 __attribute__((ext_vector_type(4)));

__device__ __forceinline__ bf16 f2bf(float x) { return (bf16)x; }

// ---------------- fused weight transpose + f32->bf16 convert (all 7 weights) ----------------
__global__ __launch_bounds__(256) void wconv_all(
    const float* __restrict__ s0, const float* __restrict__ s1, const float* __restrict__ s2,
    const float* __restrict__ s3, const float* __restrict__ s4, const float* __restrict__ s5,
    const float* __restrict__ s6,
    bf16* d0, bf16* d1, bf16* d2, bf16* d3, bf16* d4, bf16* d5, bf16* d6) {
  __shared__ float tile[64][65];
  int bid = blockIdx.x;
  const float* src; bf16* dst; int K, N, local;
  if (bid < 1024)      { src = s0; dst = d0; K = Hdim;  N = HUdim; local = bid; }
  else if (bid < 2048) { src = s1; dst = d1; K = Hdim;  N = HUdim; local = bid - 1024; }
  else if (bid < 3072) { src = s2; dst = d2; K = Hdim;  N = HUdim; local = bid - 2048; }
  else if (bid < 4096) { src = s3; dst = d3; K = HUdim; N = Hdim;  local = bid - 3072; }
  else if (bid < 5120) { src = s4; dst = d4; K = Hdim;  N = HUdim; local = bid - 4096; }
  else if (bid < 6144) { src = s5; dst = d5; K = HUdim; N = Hdim;  local = bid - 5120; }
  else                 { src = s6; dst = d6; K = Hdim;  N = Hdim;  local = bid - 6144; }
  const int nt = N >> 6;
  const int n0 = (local % nt) * 64, k0 = (local / nt) * 64;
  const int tr = threadIdx.x >> 6;   // 0..3
  const int tc = threadIdx.x & 63;
#pragma unroll
  for (int j = 0; j < 16; j++) {
    int r = j * 4 + tr;
    tile[r][tc] = src[(size_t)(k0 + r) * N + n0 + tc];
  }
  __syncthreads();
#pragma unroll
  for (int j = 0; j < 16; j++) {
    int r = j * 4 + tr;
    dst[(size_t)(n0 + r) * K + k0 + tc] = f2bf(tile[tc][r]);
  }
}

// ---------------- block reduction helper (256 threads, 4 values) ----------------
__device__ __forceinline__ void block_reduce4(float v[4], float* sm) {
#pragma unroll
  for (int off = 32; off > 0; off >>= 1) {
#pragma unroll
    for (int i = 0; i < 4; i++) v[i] += __shfl_down(v[i], off, 64);
  }
  const int w = threadIdx.x >> 6;
  if ((threadIdx.x & 63) == 0) {
#pragma unroll
    for (int i = 0; i < 4; i++) sm[w * 4 + i] = v[i];
  }
  __syncthreads();
#pragma unroll
  for (int i = 0; i < 4; i++) v[i] = sm[i] + sm[4 + i] + sm[8 + i] + sm[12 + i];
  __syncthreads();
}

// ---------------- ln0 + pre-LN + shift + TM mixes ----------------
__global__ __launch_bounds__(256) void ln_mix_tm(
    const float* __restrict__ x,
    const float* __restrict__ g0, const float* __restrict__ b0,
    const float* __restrict__ g1, const float* __restrict__ b1,
    const float* __restrict__ mk, const float* __restrict__ mv, const float* __restrict__ mr,
    float* __restrict__ x0, bf16* __restrict__ xk, bf16* __restrict__ xv, bf16* __restrict__ xr) {
  __shared__ float sm[16];
  const int bid = blockIdx.x;
  const int t = bid & (Tdim - 1);
  const int tid = threadIdx.x;
  const bool havep = (t > 0);
  const float hp = havep ? 1.f : 0.f;
  const float* rowc = x + (size_t)bid * Hdim;
  const float* rowp = havep ? (rowc - Hdim) : rowc;  // always in-bounds

  float c[4], p[4];
#pragma unroll
  for (int j = 0; j < 4; j++) c[j] = rowc[tid * 4 + j];
#pragma unroll
  for (int j = 0; j < 4; j++) p[j] = rowp[tid * 4 + j] * hp;

  float red[4] = {0.f, 0.f, 0.f, 0.f};
#pragma unroll
  for (int j = 0; j < 4; j++) { red[0] += c[j]; red[1] += c[j]*c[j]; red[2] += p[j]; red[3] += p[j]*p[j]; }
  block_reduce4(red, sm);
  const float inv = 1.f / Hdim;
  float mc = red[0]*inv, vc = red[1]*inv - mc*mc;
  float mp = red[2]*inv, vp = red[3]*inv - mp*mp;
  float sc = rsqrtf(vc + 1e-5f), sp = rsqrtf(vp + 1e-5f);

  float yc[4], yp[4];
#pragma unroll
  for (int j = 0; j < 4; j++) {
    int i = tid * 4 + j;
    yc[j] = (c[j] - mc) * sc * g0[i] + b0[i];
    yp[j] = ((p[j] - mp) * sp * g0[i] + b0[i]) * hp;
    x0[(size_t)bid * Hdim + i] = yc[j];
  }

  float r2[4] = {0.f, 0.f, 0.f, 0.f};
#pragma unroll
  for (int j = 0; j < 4; j++) { r2[0] += yc[j]; r2[1] += yc[j]*yc[j]; r2[2] += yp[j]; r2[3] += yp[j]*yp[j]; }
  block_reduce4(r2, sm);
  float mc2 = r2[0]*inv, vc2 = r2[1]*inv - mc2*mc2;
  float mp2 = r2[2]*inv, vp2 = r2[3]*inv - mp2*mp2;
  float sc2 = rsqrtf(vc2 + 1e-5f), sp2 = rsqrtf(vp2 + 1e-5f);

#pragma unroll
  for (int j = 0; j < 4; j++) {
    int i = tid * 4 + j;
    float xnc = (yc[j] - mc2) * sc2 * g1[i] + b1[i];
    float xnp = ((yp[j] - mp2) * sp2 * g1[i] + b1[i]) * hp;
    size_t o = (size_t)bid * Hdim + i;
    float a;
    a = mk[i]; xk[o] = f2bf(xnc * a + xnp * (1.f - a));
    a = mv[i]; xv[o] = f2bf(xnc * a + xnp * (1.f - a));
    a = mr[i]; xr[o] = f2bf(xnc * a + xnp * (1.f - a));
  }
}

// ---------------- post-LN + shift + CM mixes ----------------
__global__ __launch_bounds__(256) void ln_mix_cm(
    const float* __restrict__ xin,
    const float* __restrict__ g, const float* __restrict__ bb,
    const float* __restrict__ mk, const float* __restrict__ mr,
    bf16* __restrict__ xk, bf16* __restrict__ xr) {
  __shared__ float sm[16];
  const int bid = blockIdx.x;
  const int t = bid & (Tdim - 1);
  const int tid = threadIdx.x;
  const bool havep = (t > 0);
  const float hp = havep ? 1.f : 0.f;
  const float* rowc = xin + (size_t)bid * Hdim;
  const float* rowp = havep ? (rowc - Hdim) : rowc;

  float c[4], p[4];
#pragma unroll
  for (int j = 0; j < 4; j++) c[j] = rowc[tid * 4 + j];
#pragma unroll
  for (int j = 0; j < 4; j++) p[j] = rowp[tid * 4 + j] * hp;

  float red[4] = {0.f, 0.f, 0.f, 0.f};
#pragma unroll
  for (int j = 0; j < 4; j++) { red[0] += c[j]; red[1] += c[j]*c[j]; red[2] += p[j]; red[3] += p[j]*p[j]; }
  block_reduce4(red, sm);
  const float inv = 1.f / Hdim;
  float mc = red[0]*inv, vc = red[1]*inv - mc*mc;
  float mp = red[2]*inv, vp = red[3]*inv - mp*mp;
  float sc = rsqrtf(vc + 1e-5f), sp = rsqrtf(vp + 1e-5f);

#pragma unroll
  for (int j = 0; j < 4; j++) {
    int i = tid * 4 + j;
    float xnc = (c[j] - mc) * sc * g[i] + bb[i];
    float xnp = ((p[j] - mp) * sp * g[i] + bb[i]) * hp;
    size_t o = (size_t)bid * Hdim + i;
    float a;
    a = mk[i]; xk[o] = f2bf(xnc * a + xnp * (1.f - a));
    a = mr[i]; xr[o] = f2bf(xnc * a + xnp * (1.f - a));
  }
}

// ---------------- WKV parallel scan (2 channels/thread, bf16x2 loads) — R4-measured ----------------
__global__ __launch_bounds__(64) void wkv_part(
    const bf16* __restrict__ Kb, const bf16* __restrict__ Vb,
    float* __restrict__ stK, float* __restrict__ stKV,
    const float* __restrict__ tdec) {
  const int seg = blockIdx.x & (NSEG - 1);
  const int rest = blockIdx.x >> 4;       // b*16 + g
  const int b = rest >> 4, g = rest & 15;
  const int c = (g << 7) + (threadIdx.x << 1);
  const float d0 = __expf(-__expf(tdec[c]));
  const float d1 = __expf(-__expf(tdec[c + 1]));
  size_t base = ((size_t)b * Tdim + (size_t)seg * SEGL) * CHUNK + c;
  float sk0 = 0.f, skv0 = 0.f, sk1 = 0.f, skv1 = 0.f;
  for (int t0 = 0; t0 < SEGL; t0 += SCHUNK) {
    bf16x2 kk[SCHUNK], vv[SCHUNK];
#pragma unroll
    for (int j = 0; j < SCHUNK; j++) {
      size_t idx = base + (size_t)(t0 + j) * CHUNK;
      kk[j] = *(const bf16x2*)(Kb + idx);
      vv[j] = *(const bf16x2*)(Vb + idx);
    }
#pragma unroll
    for (int j = 0; j < SCHUNK; j++) {
      float k0 = (float)kk[j][0], k1 = (float)kk[j][1];
      float v0 = (float)vv[j][0], v1 = (float)vv[j][1];
      sk0  = fmaf(d0, sk0, k0);   skv0 = fmaf(d0, skv0, k0 * v0);
      sk1  = fmaf(d1, sk1, k1);   skv1 = fmaf(d1, skv1, k1 * v1);
    }
  }
  size_t so = ((size_t)seg * Bdim + b) * CHUNK + c;
  stK[so]      = sk0;  stK[so + 1]  = sk1;
  stKV[so]     = skv0; stKV[so + 1] = skv1;
}

__global__ __launch_bounds__(64) void wkv_emit(
    const bf16* __restrict__ Kb, const bf16* __restrict__ Vb,
    const bf16* SRb, bf16* Pb,   // SRb/Pb alias: per-element read-before-write
    const float* __restrict__ stK, const float* __restrict__ stKV,
    const float* __restrict__ tdec, const float* __restrict__ tfst) {
  const int seg = blockIdx.x & (NSEG - 1);
  const int rest = blockIdx.x >> 4;
  const int b = rest >> 4, g = rest & 15;
  const int c = (g << 7) + (threadIdx.x << 1);
  const float ed0 = __expf(tdec[c]),     ed1 = __expf(tdec[c + 1]);
  const float d0  = __expf(-ed0),        d1  = __expf(-ed1);
  const float df0 = __expf(-ed0 * (float)SEGL);
  const float df1 = __expf(-ed1 * (float)SEGL);
  const float f0  = __expf(tfst[c]),     f1  = __expf(tfst[c + 1]);

  float sk0 = 0.f, skv0 = 0.f, sk1 = 0.f, skv1 = 0.f;
  for (int j = 0; j < seg; j++) {
    size_t so = ((size_t)j * Bdim + b) * CHUNK + c;
    sk0  = fmaf(df0, sk0,  stK[so]);      sk1  = fmaf(df1, sk1,  stK[so + 1]);
    skv0 = fmaf(df0, skv0, stKV[so]);     skv1 = fmaf(df1, skv1, stKV[so + 1]);
  }

  size_t base = ((size_t)b * Tdim + (size_t)seg * SEGL) * CHUNK + c;
  for (int t0 = 0; t0 < SEGL; t0 += SCHUNK) {
    bf16x2 kk[SCHUNK], vv[SCHUNK], rr[SCHUNK];
#pragma unroll
    for (int j = 0; j < SCHUNK; j++) {
      size_t idx = base + (size_t)(t0 + j) * CHUNK;
      kk[j] = *(const bf16x2*)(Kb + idx);
      vv[j] = *(const bf16x2*)(Vb + idx);
      rr[j] = *(const bf16x2*)(SRb + idx);
    }
#pragma unroll
    for (int j = 0; j < SCHUNK; j++) {
      size_t idx = base + (size_t)(t0 + j) * CHUNK;
      float k0 = (float)kk[j][0], k1 = (float)kk[j][1];
      float v0 = (float)vv[j][0], v1 = (float)vv[j][1];
      float kv0 = k0 * v0, kv1 = k1 * v1;
      float wk0  = fmaf(f0, k0, sk0) + 1e-8f;
      float wk1  = fmaf(f1, k1, sk1) + 1e-8f;
      float wkv0 = fmaf(f0, kv0, skv0);
      float wkv1 = fmaf(f1, kv1, skv1);
      bf16x2 out;
      out[0] = f2bf((float)rr[j][0] * wkv0 * __builtin_amdgcn_rcpf(wk0));
      out[1] = f2bf((float)rr[j][1] * wkv1 * __builtin_amdgcn_rcpf(wk1));
      *(bf16x2*)(Pb + idx) = out;
      sk0  = fmaf(d0, sk0, k0);   skv0 = fmaf(d0, skv0, kv0);
      sk1  = fmaf(d1, sk1, k1);   skv1 = fmaf(d1, skv1, kv1);
    }
  }
}

// ---------------- shared helpers ----------------
__device__ __forceinline__ void gld_lds(const bf16* g, bf16* l) {
  __builtin_amdgcn_global_load_lds(
      (const __attribute__((address_space(1))) void*)(g),
      (__attribute__((address_space(3))) void*)(l),
      16, 0, 0);
}

// XCD-aware swizzle: xcd=s%8 owns m-band; n in groups of 2, m fastest.
__device__ __forceinline__ void swz(int s, int gm, int& m_t, int& n_t) {
  const int mpx  = gm >> 3;        // gm % 8 == 0 at all call sites
  const int xcd  = s & 7;
  const int ss   = s >> 3;
  const int pass = mpx << 1;
  const int ng   = ss / pass;
  const int rem  = ss - ng * pass;
  m_t = xcd * mpx + (rem >> 1);
  n_t = (ng << 1) + (rem & 1);
}

enum { E_EXP = 0, E_BF16 = 1, E_SIG = 2, E_ADD1 = 3, E_SILU = 4, E_F32 = 5, E_SIGADD2 = 6 };

template <int EPI>
__device__ __forceinline__ void epilogue(
    floatx4 acc[4][4], void* Cout, const void* aux1, const void* aux2,
    long m0, long n0, int ldc, int lane, int wm, int wn) {
  const int r0 = wm * 64 + ((lane >> 4) << 2);
  const int c0 = wn * 64 + (lane & 15);
#pragma unroll
  for (int mt = 0; mt < 4; mt++) {
#pragma unroll
    for (int i = 0; i < 4; i++) {
      long r = m0 + r0 + mt * 16 + i;
      long bidx = r * (long)ldc + n0 + c0;
#pragma unroll
      for (int nt = 0; nt < 4; nt++) {
        long idx = bidx + nt * 16;
        float v = acc[mt][nt][i];
        if constexpr (EPI == E_EXP) {
          ((bf16*)Cout)[idx] = f2bf(__expf(fminf(v, 60.f)));
        } else if constexpr (EPI == E_BF16) {
          ((bf16*)Cout)[idx] = f2bf(v);
        } else if constexpr (EPI == E_SIG) {
          ((bf16*)Cout)[idx] = f2bf(1.f / (1.f + __expf(-v)));
        } else if constexpr (EPI == E_ADD1) {
          float prev = ((const float*)aux1)[idx];   // may alias Cout (same idx)
          ((float*)Cout)[idx] = v + prev;
        } else if constexpr (EPI == E_SILU) {
          ((bf16*)Cout)[idx] = f2bf(v / (1.f + __expf(-v)));
        } else if constexpr (EPI == E_F32) {
          ((float*)Cout)[idx] = v;
        } else {  // E_SIGADD2
          float a1 = ((const float*)aux1)[idx];
          float a2 = ((const float*)aux2)[idx];
          ((float*)Cout)[idx] = a1 + 1.f / (1.f + __expf(-v)) + a2;
        }
      }
    }
  }
}

// =====================================================================================
// 256x128-tile GEMM core, BK=64, TRIPLE-buffered LDS (3 x 48 KiB = 144 KiB), 8 waves
// (4M x 2N, 64x64 output each), ONE barrier + ONE counted vmcnt per K-iter.
// (R4-measured version.) Exit state: per-wave vmcnt==0, all own ds-reads drained
// (lgkmcnt(0) precedes final MFMAs) — callers may __syncthreads() and re-run.
// =====================================================================================
__device__ __forceinline__ void mm_core_n128(
    const bf16* __restrict__ A, const bf16* __restrict__ Bt,
    int lda, int ldb, int K, long m0, long n0,
    int wv, int lane, bf16* Lds, floatx4 acc[4][4]) {
  const int rl  = lane >> 2;
  const int scol = (((lane & 3) - ((lane >> 3) & 3)) & 3) * 8;  // phase-swizzled k-slot
  const bf16* gA = A + (m0 + wv * 16 + rl) * (long)lda + scol;
  const bf16* gB = Bt + (n0 + wv * 16 + rl) * (long)ldb + scol;
  bf16* lA = Lds + wv * 512;            // + buf*16384 + h*4096; second k-panel +8192
  bf16* lB = Lds + 49152 + wv * 512;    // + buf*8192;           second k-panel +4096

  const int wm = wv >> 1, wn = wv & 1;
  const int pg = ((lane >> 4) + ((lane >> 1) & 3)) & 3;
  const bf16* fa0 = Lds + (wm * 64 + (lane & 15)) * 32 + pg * 8;
  const bf16* fb0 = Lds + 49152 + (wn * 64 + (lane & 15)) * 32 + pg * 8;

#define STGA_N(buf, h, kt) do { \
    const bf16* _s = gA + (long)(h) * 128 * lda + (long)(kt) * 64; \
    bf16* _d = lA + (buf) * 16384 + (h) * 4096; \
    gld_lds(_s, _d); gld_lds(_s + 32, _d + 8192); } while (0)
#define STGB_N(buf, kt) do { \
    const bf16* _s = gB + (long)(kt) * 64; \
    bf16* _d = lB + (buf) * 8192; \
    gld_lds(_s, _d); gld_lds(_s + 32, _d + 4096); } while (0)

  STGA_N(0, 0, 0); STGA_N(0, 1, 0); STGB_N(0, 0);
  STGA_N(1, 0, 1); STGA_N(1, 1, 1); STGB_N(1, 1);
  asm volatile("s_waitcnt vmcnt(6)" ::: "memory");
  __builtin_amdgcn_s_barrier();

  const int niter = K >> 6;            // K % 64 == 0
  int p = 0;
  for (int it = 0; it < niter; ++it) {
    const int q = (p >= 1) ? p - 1 : p + 2;      // (p+2)%3
    const bool dostage = (it <= niter - 3);
    const bf16* fa = fa0 + p * 16384;
    const bf16* fb = fb0 + p * 8192;

    // ---- kh = 0 ----
    bf16x8 a0[4], b0v[4];
#pragma unroll
    for (int i = 0; i < 4; ++i) {
      a0[i]  = *(const bf16x8*)(fa + i * 512);
      b0v[i] = *(const bf16x8*)(fb + i * 512);
    }
    __builtin_amdgcn_sched_barrier(0);
    if (dostage) { STGA_N(q, 0, it + 2); STGA_N(q, 1, it + 2); }
    asm volatile("s_waitcnt lgkmcnt(0)" ::: "memory");
    __builtin_amdgcn_s_setprio(1);
#pragma unroll
    for (int mf = 0; mf < 4; ++mf)
#pragma unroll
      for (int nf = 0; nf < 4; ++nf)
        acc[mf][nf] = __builtin_amdgcn_mfma_f32_16x16x32_bf16(a0[mf], b0v[nf], acc[mf][nf], 0, 0, 0);
    __builtin_amdgcn_s_setprio(0);

    // ---- kh = 1 ----
    bf16x8 a1[4], b1v[4];
#pragma unroll
    for (int i = 0; i < 4; ++i) {
      a1[i]  = *(const bf16x8*)(fa + 8192 + i * 512);
      b1v[i] = *(const bf16x8*)(fb + 4096 + i * 512);
    }
    __builtin_amdgcn_sched_barrier(0);
    if (dostage) STGB_N(q, it + 2);
    asm volatile("s_waitcnt lgkmcnt(0)" ::: "memory");
    __builtin_amdgcn_s_setprio(1);
#pragma unroll
    for (int mf = 0; mf < 4; ++mf)
#pragma unroll
      for (int nf = 0; nf < 4; ++nf)
        acc[mf][nf] = __builtin_amdgcn_mfma_f32_16x16x32_bf16(a1[mf], b1v[nf], acc[mf][nf], 0, 0, 0);
    __builtin_amdgcn_s_setprio(0);

    if (it < niter - 1) {
      if (dostage) asm volatile("s_waitcnt vmcnt(6)" ::: "memory");
      else         asm volatile("s_waitcnt vmcnt(0)" ::: "memory");
      __builtin_amdgcn_s_barrier();
    }
    p = (p == 2) ? 0 : p + 1;
  }
#undef STGA_N
#undef STGB_N
}

// 256x128-tile kernel: grid = (M/256)*(N/128) blocks.
template <int EPI>
__global__ __launch_bounds__(512, 2) void gemm8n(
    const bf16* __restrict__ A, const bf16* __restrict__ Bt,
    void* Cout, const void* aux1, const void* aux2,
    int lda, int ldb, int ldc, int K, int gm, int gn) {
  __shared__ __align__(16) bf16 Lds[73728];   // 144 KiB
  const int tid = threadIdx.x;
  const int lane = tid & 63;
  const int wv = tid >> 6;
  int m_t, n_t;
  swz(blockIdx.x, gm, m_t, n_t);
  const long m0 = (long)m_t * 256, n0 = (long)n_t * 128;
  floatx4 acc[4][4];
#pragma unroll
  for (int i = 0; i < 4; i++)
#pragma unroll
    for (int j = 0; j < 4; j++) acc[i][j] = (floatx4){0.f, 0.f, 0.f, 0.f};
  mm_core_n128(A, Bt, lda, ldb, K, m0, n0, wv, lane, Lds, acc);
  const int wm = wv >> 1, wn = wv & 1;   // 4M x 2N waves, 64x64 each
  epilogue<EPI>(acc, Cout, aux1, aux2, m0, n0, ldc, lane, wm, wn);
}

// ---------------- dual GEMM: d_out = xres + sigmoid(xr2@cWr) + hbuf@cWv ----------------
// Two back-to-back n128 cores on the same output tile; acc1 held in VGPRs across core-2.
// __syncthreads() between cores: core-1 exits with vmcnt=0 per-wave and its ds-reads
// drained, so the barrier makes LDS reuse by core-2's prologue race-free.
__global__ __launch_bounds__(512, 2) void gemm_dual(
    const bf16* __restrict__ A1, const bf16* __restrict__ Bt1,   // hbuf [M,HU], cWvT [H,HU]
    const bf16* __restrict__ A2, const bf16* __restrict__ Bt2,   // xr2 [M,H],  cWrT [H,H]
    float* __restrict__ Cout, const float* __restrict__ xres,
    int gm, int gn) {
  __shared__ __align__(16) bf16 Lds[73728];   // 144 KiB
  const int tid = threadIdx.x;
  const int lane = tid & 63;
  const int wv = tid >> 6;
  int m_t, n_t;
  swz(blockIdx.x, gm, m_t, n_t);
  const long m0 = (long)m_t * 256, n0 = (long)n_t * 128;

  floatx4 acc1[4][4], acc2[4][4];
#pragma unroll
  for (int i = 0; i < 4; i++)
#pragma unroll
    for (int j = 0; j < 4; j++) {
      acc1[i][j] = (floatx4){0.f, 0.f, 0.f, 0.f};
      acc2[i][j] = (floatx4){0.f, 0.f, 0.f, 0.f};
    }

  mm_core_n128(A1, Bt1, HUdim, HUdim, HUdim, m0, n0, wv, lane, Lds, acc1);
  __syncthreads();
  mm_core_n128(A2, Bt2, Hdim, Hdim, Hdim, m0, n0, wv, lane, Lds, acc2);

  const int wm = wv >> 1, wn = wv & 1;
  const int r0 = wm * 64 + ((lane >> 4) << 2);
  const int c0 = wn * 64 + (lane & 15);
#pragma unroll
  for (int mt = 0; mt < 4; ++mt) {
#pragma unroll
    for (int i = 0; i < 4; ++i) {
      long r = m0 + r0 + mt * 16 + i;
      long bidx = r * (long)Hdim + n0 + c0;
#pragma unroll
      for (int nt = 0; nt < 4; ++nt) {
        long idx = bidx + nt * 16;
        float vr = acc2[mt][nt][i];
        Cout[idx] = xres[idx] + 1.f / (1.f + __expf(-vr)) + acc1[mt][nt][i];
      }
    }
  }
}

// =====================================================================================
// 8-phase 256x256 GEMM core (zigzag quadrant order) — R2/R4-measured version.
// =====================================================================================
__device__ __forceinline__ void mm_core256(
    const bf16* __restrict__ A, const bf16* __restrict__ Bt,
    int lda, int ldb, int K, long m0, long n0,
    int wv, int lane, bf16* Lds, floatx4 acc[8][4]) {
  const int wm = wv >> 2, wn = wv & 3;
  const int rA0 = wm * 128 + (wv & 3) * 16;
  const int rB0 = (wv >> 1) * 64 + (wv & 1) * 16;
  const int rl  = lane >> 2;
  const int scol = (((lane & 3) - ((lane >> 3) & 3)) & 3) * 8;
  const bf16* gA = A + (m0 + rA0 + rl) * (long)lda + scol;
  const bf16* gB = Bt + (n0 + rB0 + rl) * (long)ldb + scol;
  bf16* lA = Lds + rA0 * 32;
  bf16* lB = Lds + 16384 + rB0 * 32;

  const int pg = ((lane >> 4) + ((lane >> 1) & 3)) & 3;
  const bf16* fa0 = Lds + (wm * 128 + (lane & 15)) * 32 + pg * 8;
  const bf16* fb0 = Lds + 16384 + (wn * 64 + (lane & 15)) * 32 + pg * 8;

#define STGA8(buf, h, kt) do { \
    const bf16* _s = gA + (long)(h) * 64 * lda + (kt) * 64; \
    bf16* _d = lA + (buf) * 32768 + (h) * 2048; \
    gld_lds(_s, _d); gld_lds(_s + 32, _d + 8192); } while (0)
#define STGB8(buf, h, kt) do { \
    const bf16* _s = gB + (long)(h) * 32 * ldb + (kt) * 64; \
    bf16* _d = lB + (buf) * 32768 + (h) * 1024; \
    gld_lds(_s, _d); gld_lds(_s + 32, _d + 8192); } while (0)

  STGA8(0, 0, 0); STGB8(0, 0, 0); STGB8(0, 1, 0); STGA8(0, 1, 0);
  STGA8(1, 0, 1); STGB8(1, 0, 1); STGB8(1, 1, 1);
  asm volatile("s_waitcnt vmcnt(10)" ::: "memory");
  __builtin_amdgcn_s_barrier();

  const int niter = K >> 7;            // K % 128 == 0
  bf16x8 a[4][2];
  bf16x8 b[2][2][2];
  for (int it = 0; it < niter; ++it) {
    const int kt0 = it << 1;
    const bool notlast = (it != niter - 1);
#pragma unroll
    for (int ph = 0; ph < 8; ++ph) {
      const int q   = ph & 3;
      const int buf = ph >> 2;
      const int mq  = q >> 1;
      const int nq  = (q >> 1) ^ (q & 1);
      const bf16* fa = fa0 + buf * 32768 + mq * 2048;
      const bf16* fb = fb0 + buf * 32768 + nq * 1024;
      if (q == 0) {
#pragma unroll
        for (int mf = 0; mf < 4; ++mf) {
          a[mf][0] = *(const bf16x8*)(fa + mf * 512);
          a[mf][1] = *(const bf16x8*)(fa + mf * 512 + 8192);
        }
#pragma unroll
        for (int nf = 0; nf < 2; ++nf) {
          b[0][nf][0] = *(const bf16x8*)(fb + nf * 512);
          b[0][nf][1] = *(const bf16x8*)(fb + nf * 512 + 8192);
        }
      } else if (q == 1) {
#pragma unroll
        for (int nf = 0; nf < 2; ++nf) {
          b[1][nf][0] = *(const bf16x8*)(fb + nf * 512);
          b[1][nf][1] = *(const bf16x8*)(fb + nf * 512 + 8192);
        }
      } else if (q == 2) {
#pragma unroll
        for (int mf = 0; mf < 4; ++mf) {
          a[mf][0] = *(const bf16x8*)(fa + mf * 512);
          a[mf][1] = *(const bf16x8*)(fa + mf * 512 + 8192);
        }
      }
      __builtin_amdgcn_sched_barrier(0);
      if (ph == 0)            STGA8(1, 1, kt0 + 1);
      else if (notlast) {
        if (ph == 1)      STGA8(0, 0, kt0 + 2);
        else if (ph == 2) STGB8(0, 0, kt0 + 2);
        else if (ph == 3) STGB8(0, 1, kt0 + 2);
        else if (ph == 4) STGA8(0, 1, kt0 + 2);
        else if (ph == 5) STGA8(1, 0, kt0 + 3);
        else if (ph == 6) STGB8(1, 0, kt0 + 3);
        else              STGB8(1, 1, kt0 + 3);
      }
      if (notlast) {
        if (ph == 0 || ph == 1 || ph == 4 || ph == 5)
          asm volatile("s_waitcnt vmcnt(10)" ::: "memory");
        else if (ph == 3 || ph == 7)
          asm volatile("s_waitcnt vmcnt(12)" ::: "memory");
      } else {
        if (ph == 0)      asm volatile("s_waitcnt vmcnt(10)" ::: "memory");
        else if (ph == 1) asm volatile("s_waitcnt vmcnt(0)" ::: "memory");
      }
      if (q != 3) {
        __builtin_amdgcn_s_barrier();
        asm volatile("s_waitcnt lgkmcnt(0)" ::: "memory");
      }
      __builtin_amdgcn_s_setprio(1);
#pragma unroll
      for (int mf = 0; mf < 4; ++mf)
#pragma unroll
        for (int nf = 0; nf < 2; ++nf) {
          acc[mq*4+mf][nq*2+nf] = __builtin_amdgcn_mfma_f32_16x16x32_bf16(
              a[mf][0], b[nq][nf][0], acc[mq*4+mf][nq*2+nf], 0, 0, 0);
          acc[mq*4+mf][nq*2+nf] = __builtin_amdgcn_mfma_f32_16x16x32_bf16(
              a[mf][1], b[nq][nf][1], acc[mq*4+mf][nq*2+nf], 0, 0, 0);
        }
      __builtin_amdgcn_s_setprio(0);
      __builtin_amdgcn_s_barrier();
    }
  }
#undef STGA8
#undef STGB8
}

template <int EPI>
__global__ __launch_bounds__(512, 2) void gemm8(
    const bf16* __restrict__ A, const bf16* __restrict__ Bt,
    void* Cout, const void* aux1, const void* aux2,
    int lda, int ldb, int ldc, int K, int gm, int gn) {
  __shared__ __align__(16) bf16 Lds[65536];   // 128 KiB
  const int tid = threadIdx.x;
  const int lane = tid & 63;
  const int wv = tid >> 6;
  int m_t, n_t;
  swz(blockIdx.x, gm, m_t, n_t);
  const long m0 = (long)m_t * 256, n0 = (long)n_t * 256;
  floatx4 acc[8][4];
#pragma unroll
  for (int i = 0; i < 8; i++)
#pragma unroll
    for (int j = 0; j < 4; j++) acc[i][j] = (floatx4){0.f, 0.f, 0.f, 0.f};
  mm_core256(A, Bt, lda, ldb, K, m0, n0, wv, lane, Lds, acc);

  const int wm = wv >> 2, wn = wv & 3;
  const int r0 = wm * 128 + ((lane >> 4) << 2);
  const int c0 = wn * 64 + (lane & 15);
#pragma unroll
  for (int mf = 0; mf < 8; ++mf) {
#pragma unroll
    for (int i = 0; i < 4; ++i) {
      long r = m0 + r0 + mf * 16 + i;
      long bidx = r * (long)ldc + n0 + c0;
#pragma unroll
      for (int nf = 0; nf < 4; ++nf) {
        long idx = bidx + nf * 16;
        float v = acc[mf][nf][i];
        if constexpr (EPI == E_SILU) {
          ((bf16*)Cout)[idx] = f2bf(v / (1.f + __expf(-v)));
        } else if constexpr (EPI == E_BF16) {
          ((bf16*)Cout)[idx] = f2bf(v);
        } else if constexpr (EPI == E_F32) {
          ((float*)Cout)[idx] = v;
        } else if constexpr (EPI == E_ADD1) {
          float prev = ((const float*)aux1)[idx];
          ((float*)Cout)[idx] = v + prev;
        }
      }
    }
  }
}

// ---------------- fused K/V/R projection on the 8-phase core ----------------
__global__ __launch_bounds__(512, 2) void proj8(
    const bf16* __restrict__ xk, const bf16* __restrict__ xv, const bf16* __restrict__ xr,
    const bf16* __restrict__ Wk, const bf16* __restrict__ Wv, const bf16* __restrict__ Wr,
    bf16* Kc, bf16* Vc, bf16* SRc, int gm, int gn) {
  __shared__ __align__(16) bf16 Lds[65536];   // 128 KiB
  const int per = gm * gn;
  const int sub = blockIdx.x / per;           // 0:K 1:V 2:R
  const int s   = blockIdx.x - sub * per;
  const int tid = threadIdx.x;
  const int lane = tid & 63;
  const int wv = tid >> 6;
  int m_t, n_t;
  swz(s, gm, m_t, n_t);
  const long m0 = (long)m_t * 256, n0 = (long)n_t * 256;

  const bf16* A  = (sub == 0) ? xk : (sub == 1) ? xv : xr;
  const bf16* Bt = (sub == 0) ? Wk : (sub == 1) ? Wv : Wr;
  bf16*       C  = (sub == 0) ? Kc : (sub == 1) ? Vc : SRc;

  floatx4 acc[8][4];
#pragma unroll
  for (int i = 0; i < 8; i++)
#pragma unroll
    for (int j = 0; j < 4; j++) acc[i][j] = (floatx4){0.f, 0.f, 0.f, 0.f};
  mm_core256(A, Bt, Hdim, Hdim, Hdim, m0, n0, wv, lane, Lds, acc);

  const int wm = wv >> 2, wn = wv & 3;
  const int r0 = wm * 128 + ((lane >> 4) << 2);
  const int c0 = wn * 64 + (lane & 15);
#pragma unroll
  for (int mf = 0; mf < 8; ++mf) {
#pragma unroll
    for (int i = 0; i < 4; ++i) {
      long r = m0 + r0 + mf * 16 + i;
      long bidx = r * (long)CHUNK + n0 + c0;
#pragma unroll
      for (int nf = 0; nf < 4; ++nf) {
        long idx = bidx + nf * 16;
        float v = acc[mf][nf][i];
        float o;
        if (sub == 0)      o = __expf(fminf(v, 60.f));
        else if (sub == 1) o = v;
        else               o = 1.f / (1.f + __expf(-v));
        C[idx] = f2bf(o);
      }
    }
  }
}

// ---------------- launch ----------------
extern "C" void kernel_launch(void* const* d_in, const int* in_sizes, int n_in,
                              void* d_out, int out_size, void* d_ws, size_t ws_size,
                              hipStream_t stream) {
  (void)in_sizes; (void)n_in; (void)out_size; (void)ws_size;
  const float* x        = (const float*)d_in[0];
  const float* ln0_g    = (const float*)d_in[1];
  const float* ln0_b    = (const float*)d_in[2];
  const float* pre_g    = (const float*)d_in[3];
  const float* pre_b    = (const float*)d_in[4];
  const float* post_g   = (const float*)d_in[5];
  const float* post_b   = (const float*)d_in[6];
  const float* tm_decay = (const float*)d_in[7];
  const float* tm_first = (const float*)d_in[8];
  const float* tm_mix_k = (const float*)d_in[9];
  const float* tm_mix_v = (const float*)d_in[10];
  const float* tm_mix_r = (const float*)d_in[11];
  const float* tm_Wk    = (const float*)d_in[12];
  const float* tm_Wv    = (const float*)d_in[13];
  const float* tm_Wr    = (const float*)d_in[14];
  const float* tm_Wo    = (const float*)d_in[15];
  const float* cm_mix_k = (const float*)d_in[16];
  const float* cm_mix_r = (const float*)d_in[17];
  const float* cm_Wk    = (const float*)d_in[18];
  const float* cm_Wv    = (const float*)d_in[19];
  const float* cm_Wr    = (const float*)d_in[20];

  char* ws = (char*)d_ws;
  // static layout (bytes); peak 238,026,752 (227 MiB)
  bf16*  WkT  = (bf16*)(ws + 0);          // [HU,H]
  bf16*  WvT  = (bf16*)(ws + 8388608);    // [HU,H]
  bf16*  WrT  = (bf16*)(ws + 16777216);   // [HU,H]
  bf16*  WoT  = (bf16*)(ws + 25165824);   // [H,HU]
  bf16*  cWkT = (bf16*)(ws + 33554432);   // [HU,H]
  bf16*  cWvT = (bf16*)(ws + 41943040);   // [H,HU]
  bf16*  cWrT = (bf16*)(ws + 50331648);   // [H,H]
  float* xres = (float*)(ws + 52428800);  // [M,H] f32
  bf16*  xk   = (bf16*)(ws + 85983232);   // [M,H]
  bf16*  xv   = (bf16*)(ws + 102760448);
  bf16*  xr   = (bf16*)(ws + 119537664);
  bf16*  Kc   = (bf16*)(ws + 136314880);  // [M,CHUNK]
  bf16*  Vc   = (bf16*)(ws + 169869312);  // [M,CHUNK]
  bf16*  SRc  = (bf16*)(ws + 203423744);  // [M,CHUNK], P written in place
  float* stK  = (float*)(ws + 236978176); // [NSEG,B,CHUNK] f32 (512 KiB)
  float* stKV = (float*)(ws + 237502464); // [NSEG,B,CHUNK] f32 (512 KiB)
  // CM-phase aliases (regions dead by then):
  bf16*  xk2  = (bf16*)(ws + 136314880);  // over Kc
  bf16*  xr2  = (bf16*)(ws + 153092096);  // over Kc (2nd half)
  bf16*  hbuf = (bf16*)(ws + 169869312);  // [M,HU] over Vc+SRc

  dim3 blk(256);
  wconv_all<<<6400, blk, 0, stream>>>(tm_Wk, tm_Wv, tm_Wr, tm_Wo, cm_Wk, cm_Wv, cm_Wr,
                                      WkT, WvT, WrT, WoT, cWkT, cWvT, cWrT);

  ln_mix_tm<<<Mrows, blk, 0, stream>>>(x, ln0_g, ln0_b, pre_g, pre_b,
                                       tm_mix_k, tm_mix_v, tm_mix_r, xres, xk, xv, xr);

  const int scan_grid = NSEG * Bdim * (CHUNK / 128);  // 1024 blocks (2 ch/thread)
  const int GM8 = Mrows / 256;                         // 32 (256-row tiles)
  const int GN8p = CHUNK / 256;                        // 8
  const int GNn = Hdim / 128;                          // 8 (gemm8n n-tiles)
  for (int ch = 0; ch < NCH; ch++) {
    const long woff = (long)ch * CHUNK;
    // 3 fused GEMMs on the 8-phase 256^2 core: 768 blocks = 3 full waves of 256 CUs
    proj8<<<3 * GM8 * GN8p, dim3(512), 0, stream>>>(
        xk, xv, xr, WkT + woff * Hdim, WvT + woff * Hdim, WrT + woff * Hdim,
        Kc, Vc, SRc, GM8, GN8p);

    wkv_part<<<scan_grid, dim3(64), 0, stream>>>(
        Kc, Vc, stK, stKV, tm_decay + woff);
    wkv_emit<<<scan_grid, dim3(64), 0, stream>>>(
        Kc, Vc, SRc, SRc, stK, stKV, tm_decay + woff, tm_first + woff);

    // xres += P_ch @ Wo[ch*CHUNK:,:]  -> 256x128-tile one-barrier core, 256 blocks
    gemm8n<E_ADD1><<<GM8 * GNn, dim3(512), 0, stream>>>(
        SRc, WoT + woff, xres, xres, nullptr, CHUNK, HUdim, Hdim, CHUNK, GM8, GNn);
  }

  ln_mix_cm<<<Mrows, blk, 0, stream>>>(xres, post_g, post_b, cm_mix_k, cm_mix_r, xk2, xr2);

  // hbuf = silu(xk2 @ cWk) over full HU on the 8-phase core: 512 blocks
  gemm8<E_SILU><<<GM8 * (HUdim/256), dim3(512), 0, stream>>>(
      xk2, cWkT, hbuf, nullptr, nullptr, Hdim, Hdim, HUdim, Hdim, GM8, HUdim/256);

  // d_out = xres + sigmoid(xr2 @ cWr) + hbuf @ cWv  — ONE fused dual-K kernel
  // (removes the hv f32 round-trip (67 MB) and one dispatch)
  gemm_dual<<<GM8 * GNn, dim3(512), 0, stream>>>(
      hbuf, cWvT, xr2, cWrT, (float*)d_out, xres, GM8, GNn);
}

// Round 11
// 838.159 us; speedup vs baseline: 1.2780x; 1.0031x over previous
//
#include <hip/hip_runtime.h>

#define Hdim  1024
#define Tdim  2048
#define Bdim  4
#define HUdim 4096
#define Mrows (Bdim*Tdim)   // 8192
#define CHUNK 2048          // HU processed in HUdim/CHUNK slices
#define NCH   (HUdim/CHUNK) // 2
#define NSEG  32            // T-segments for parallel scan (R10: 16->32 for 2x scan TLP)
#define SEGL  (Tdim/NSEG)   // 64
#define SCHUNK 16

typedef __bf16 bf16;
typedef __bf16 bf16x2 __attribute__((ext_vector_type(2)));
typedef __bf16 bf16x8 __attribute__((ext_vector_type(8)));
typedef float  floatx4 __attribute__((ext_vector_type(4)));

__device__ __forceinline__ bf16 f2bf(float x) { return (bf16)x; }

// ---------------- fused weight transpose + f32->bf16 convert (all 7 weights) ----------------
__global__ __launch_bounds__(256) void wconv_all(
    const float* __restrict__ s0, const float* __restrict__ s1, const float* __restrict__ s2,
    const float* __restrict__ s3, const float* __restrict__ s4, const float* __restrict__ s5,
    const float* __restrict__ s6,
    bf16* d0, bf16* d1, bf16* d2, bf16* d3, bf16* d4, bf16* d5, bf16* d6) {
  __shared__ float tile[64][65];
  int bid = blockIdx.x;
  const float* src; bf16* dst; int K, N, local;
  if (bid < 1024)      { src = s0; dst = d0; K = Hdim;  N = HUdim; local = bid; }
  else if (bid < 2048) { src = s1; dst = d1; K = Hdim;  N = HUdim; local = bid - 1024; }
  else if (bid < 3072) { src = s2; dst = d2; K = Hdim;  N = HUdim; local = bid - 2048; }
  else if (bid < 4096) { src = s3; dst = d3; K = HUdim; N = Hdim;  local = bid - 3072; }
  else if (bid < 5120) { src = s4; dst = d4; K = Hdim;  N = HUdim; local = bid - 4096; }
  else if (bid < 6144) { src = s5; dst = d5; K = HUdim; N = Hdim;  local = bid - 5120; }
  else                 { src = s6; dst = d6; K = Hdim;  N = Hdim;  local = bid - 6144; }
  const int nt = N >> 6;
  const int n0 = (local % nt) * 64, k0 = (local / nt) * 64;
  const int tr = threadIdx.x >> 6;   // 0..3
  const int tc = threadIdx.x & 63;
#pragma unroll
  for (int j = 0; j < 16; j++) {
    int r = j * 4 + tr;
    tile[r][tc] = src[(size_t)(k0 + r) * N + n0 + tc];
  }
  __syncthreads();
#pragma unroll
  for (int j = 0; j < 16; j++) {
    int r = j * 4 + tr;
    dst[(size_t)(n0 + r) * K + k0 + tc] = f2bf(tile[tc][r]);
  }
}

// ---------------- block reduction helper (256 threads, 4 values) ----------------
__device__ __forceinline__ void block_reduce4(float v[4], float* sm) {
#pragma unroll
  for (int off = 32; off > 0; off >>= 1) {
#pragma unroll
    for (int i = 0; i < 4; i++) v[i] += __shfl_down(v[i], off, 64);
  }
  const int w = threadIdx.x >> 6;
  if ((threadIdx.x & 63) == 0) {
#pragma unroll
    for (int i = 0; i < 4; i++) sm[w * 4 + i] = v[i];
  }
  __syncthreads();
#pragma unroll
  for (int i = 0; i < 4; i++) v[i] = sm[i] + sm[4 + i] + sm[8 + i] + sm[12 + i];
  __syncthreads();
}

// ---------------- ln0 + pre-LN + shift + TM mixes ----------------
__global__ __launch_bounds__(256) void ln_mix_tm(
    const float* __restrict__ x,
    const float* __restrict__ g0, const float* __restrict__ b0,
    const float* __restrict__ g1, const float* __restrict__ b1,
    const float* __restrict__ mk, const float* __restrict__ mv, const float* __restrict__ mr,
    float* __restrict__ x0, bf16* __restrict__ xk, bf16* __restrict__ xv, bf16* __restrict__ xr) {
  __shared__ float sm[16];
  const int bid = blockIdx.x;
  const int t = bid & (Tdim - 1);
  const int tid = threadIdx.x;
  const bool havep = (t > 0);
  const float hp = havep ? 1.f : 0.f;
  const float* rowc = x + (size_t)bid * Hdim;
  const float* rowp = havep ? (rowc - Hdim) : rowc;  // always in-bounds

  float c[4], p[4];
#pragma unroll
  for (int j = 0; j < 4; j++) c[j] = rowc[tid * 4 + j];
#pragma unroll
  for (int j = 0; j < 4; j++) p[j] = rowp[tid * 4 + j] * hp;

  float red[4] = {0.f, 0.f, 0.f, 0.f};
#pragma unroll
  for (int j = 0; j < 4; j++) { red[0] += c[j]; red[1] += c[j]*c[j]; red[2] += p[j]; red[3] += p[j]*p[j]; }
  block_reduce4(red, sm);
  const float inv = 1.f / Hdim;
  float mc = red[0]*inv, vc = red[1]*inv - mc*mc;
  float mp = red[2]*inv, vp = red[3]*inv - mp*mp;
  float sc = rsqrtf(vc + 1e-5f), sp = rsqrtf(vp + 1e-5f);

  float yc[4], yp[4];
#pragma unroll
  for (int j = 0; j < 4; j++) {
    int i = tid * 4 + j;
    yc[j] = (c[j] - mc) * sc * g0[i] + b0[i];
    yp[j] = ((p[j] - mp) * sp * g0[i] + b0[i]) * hp;
    x0[(size_t)bid * Hdim + i] = yc[j];
  }

  float r2[4] = {0.f, 0.f, 0.f, 0.f};
#pragma unroll
  for (int j = 0; j < 4; j++) { r2[0] += yc[j]; r2[1] += yc[j]*yc[j]; r2[2] += yp[j]; r2[3] += yp[j]*yp[j]; }
  block_reduce4(r2, sm);
  float mc2 = r2[0]*inv, vc2 = r2[1]*inv - mc2*mc2;
  float mp2 = r2[2]*inv, vp2 = r2[3]*inv - mp2*mp2;
  float sc2 = rsqrtf(vc2 + 1e-5f), sp2 = rsqrtf(vp2 + 1e-5f);

#pragma unroll
  for (int j = 0; j < 4; j++) {
    int i = tid * 4 + j;
    float xnc = (yc[j] - mc2) * sc2 * g1[i] + b1[i];
    float xnp = ((yp[j] - mp2) * sp2 * g1[i] + b1[i]) * hp;
    size_t o = (size_t)bid * Hdim + i;
    float a;
    a = mk[i]; xk[o] = f2bf(xnc * a + xnp * (1.f - a));
    a = mv[i]; xv[o] = f2bf(xnc * a + xnp * (1.f - a));
    a = mr[i]; xr[o] = f2bf(xnc * a + xnp * (1.f - a));
  }
}

// ---------------- post-LN + shift + CM mixes ----------------
__global__ __launch_bounds__(256) void ln_mix_cm(
    const float* __restrict__ xin,
    const float* __restrict__ g, const float* __restrict__ bb,
    const float* __restrict__ mk, const float* __restrict__ mr,
    bf16* __restrict__ xk, bf16* __restrict__ xr) {
  __shared__ float sm[16];
  const int bid = blockIdx.x;
  const int t = bid & (Tdim - 1);
  const int tid = threadIdx.x;
  const bool havep = (t > 0);
  const float hp = havep ? 1.f : 0.f;
  const float* rowc = xin + (size_t)bid * Hdim;
  const float* rowp = havep ? (rowc - Hdim) : rowc;

  float c[4], p[4];
#pragma unroll
  for (int j = 0; j < 4; j++) c[j] = rowc[tid * 4 + j];
#pragma unroll
  for (int j = 0; j < 4; j++) p[j] = rowp[tid * 4 + j] * hp;

  float red[4] = {0.f, 0.f, 0.f, 0.f};
#pragma unroll
  for (int j = 0; j < 4; j++) { red[0] += c[j]; red[1] += c[j]*c[j]; red[2] += p[j]; red[3] += p[j]*p[j]; }
  block_reduce4(red, sm);
  const float inv = 1.f / Hdim;
  float mc = red[0]*inv, vc = red[1]*inv - mc*mc;
  float mp = red[2]*inv, vp = red[3]*inv - mp*mp;
  float sc = rsqrtf(vc + 1e-5f), sp = rsqrtf(vp + 1e-5f);

#pragma unroll
  for (int j = 0; j < 4; j++) {
    int i = tid * 4 + j;
    float xnc = (c[j] - mc) * sc * g[i] + bb[i];
    float xnp = ((p[j] - mp) * sp * g[i] + bb[i]) * hp;
    size_t o = (size_t)bid * Hdim + i;
    float a;
    a = mk[i]; xk[o] = f2bf(xnc * a + xnp * (1.f - a));
    a = mr[i]; xr[o] = f2bf(xnc * a + xnp * (1.f - a));
  }
}

// ---------------- WKV parallel scan (2 channels/thread, bf16x2 loads) ----------------
// NSEG=32: grid = NSEG * Bdim * (CHUNK/128) = 2048 blocks of 64 threads.
__global__ __launch_bounds__(64) void wkv_part(
    const bf16* __restrict__ Kb, const bf16* __restrict__ Vb,
    float* __restrict__ stK, float* __restrict__ stKV,
    const float* __restrict__ tdec) {
  const int seg = blockIdx.x & (NSEG - 1);
  const int rest = blockIdx.x >> 5;       // b*16 + g   (shift = log2(NSEG))
  const int b = rest >> 4, g = rest & 15;
  const int c = (g << 7) + (threadIdx.x << 1);
  const float d0 = __expf(-__expf(tdec[c]));
  const float d1 = __expf(-__expf(tdec[c + 1]));
  size_t base = ((size_t)b * Tdim + (size_t)seg * SEGL) * CHUNK + c;
  float sk0 = 0.f, skv0 = 0.f, sk1 = 0.f, skv1 = 0.f;
  for (int t0 = 0; t0 < SEGL; t0 += SCHUNK) {
    bf16x2 kk[SCHUNK], vv[SCHUNK];
#pragma unroll
    for (int j = 0; j < SCHUNK; j++) {
      size_t idx = base + (size_t)(t0 + j) * CHUNK;
      kk[j] = *(const bf16x2*)(Kb + idx);
      vv[j] = *(const bf16x2*)(Vb + idx);
    }
#pragma unroll
    for (int j = 0; j < SCHUNK; j++) {
      float k0 = (float)kk[j][0], k1 = (float)kk[j][1];
      float v0 = (float)vv[j][0], v1 = (float)vv[j][1];
      sk0  = fmaf(d0, sk0, k0);   skv0 = fmaf(d0, skv0, k0 * v0);
      sk1  = fmaf(d1, sk1, k1);   skv1 = fmaf(d1, skv1, k1 * v1);
    }
  }
  size_t so = ((size_t)seg * Bdim + b) * CHUNK + c;
  stK[so]      = sk0;  stK[so + 1]  = sk1;
  stKV[so]     = skv0; stKV[so + 1] = skv1;
}

__global__ __launch_bounds__(64) void wkv_emit(
    const bf16* __restrict__ Kb, const bf16* __restrict__ Vb,
    const bf16* SRb, bf16* Pb,   // SRb/Pb alias: per-element read-before-write
    const float* __restrict__ stK, const float* __restrict__ stKV,
    const float* __restrict__ tdec, const float* __restrict__ tfst) {
  const int seg = blockIdx.x & (NSEG - 1);
  const int rest = blockIdx.x >> 5;       // shift = log2(NSEG)
  const int b = rest >> 4, g = rest & 15;
  const int c = (g << 7) + (threadIdx.x << 1);
  const float ed0 = __expf(tdec[c]),     ed1 = __expf(tdec[c + 1]);
  const float d0  = __expf(-ed0),        d1  = __expf(-ed1);
  const float df0 = __expf(-ed0 * (float)SEGL);
  const float df1 = __expf(-ed1 * (float)SEGL);
  const float f0  = __expf(tfst[c]),     f1  = __expf(tfst[c + 1]);

  float sk0 = 0.f, skv0 = 0.f, sk1 = 0.f, skv1 = 0.f;
  for (int j = 0; j < seg; j++) {
    size_t so = ((size_t)j * Bdim + b) * CHUNK + c;
    sk0  = fmaf(df0, sk0,  stK[so]);      sk1  = fmaf(df1, sk1,  stK[so + 1]);
    skv0 = fmaf(df0, skv0, stKV[so]);     skv1 = fmaf(df1, skv1, stKV[so + 1]);
  }

  size_t base = ((size_t)b * Tdim + (size_t)seg * SEGL) * CHUNK + c;
  for (int t0 = 0; t0 < SEGL; t0 += SCHUNK) {
    bf16x2 kk[SCHUNK], vv[SCHUNK], rr[SCHUNK];
#pragma unroll
    for (int j = 0; j < SCHUNK; j++) {
      size_t idx = base + (size_t)(t0 + j) * CHUNK;
      kk[j] = *(const bf16x2*)(Kb + idx);
      vv[j] = *(const bf16x2*)(Vb + idx);
      rr[j] = *(const bf16x2*)(SRb + idx);
    }
#pragma unroll
    for (int j = 0; j < SCHUNK; j++) {
      size_t idx = base + (size_t)(t0 + j) * CHUNK;
      float k0 = (float)kk[j][0], k1 = (float)kk[j][1];
      float v0 = (float)vv[j][0], v1 = (float)vv[j][1];
      float kv0 = k0 * v0, kv1 = k1 * v1;
      float wk0  = fmaf(f0, k0, sk0) + 1e-8f;
      float wk1  = fmaf(f1, k1, sk1) + 1e-8f;
      float wkv0 = fmaf(f0, kv0, skv0);
      float wkv1 = fmaf(f1, kv1, skv1);
      bf16x2 out;
      out[0] = f2bf((float)rr[j][0] * wkv0 * __builtin_amdgcn_rcpf(wk0));
      out[1] = f2bf((float)rr[j][1] * wkv1 * __builtin_amdgcn_rcpf(wk1));
      *(bf16x2*)(Pb + idx) = out;
      sk0  = fmaf(d0, sk0, k0);   skv0 = fmaf(d0, skv0, kv0);
      sk1  = fmaf(d1, sk1, k1);   skv1 = fmaf(d1, skv1, kv1);
    }
  }
}

// ---------------- shared helpers ----------------
__device__ __forceinline__ void gld_lds(const bf16* g, bf16* l) {
  __builtin_amdgcn_global_load_lds(
      (const __attribute__((address_space(1))) void*)(g),
      (__attribute__((address_space(3))) void*)(l),
      16, 0, 0);
}

// XCD-aware swizzle: xcd=s%8 owns m-band; n in groups of 2, m fastest.
__device__ __forceinline__ void swz(int s, int gm, int& m_t, int& n_t) {
  const int mpx  = gm >> 3;        // gm % 8 == 0 at all call sites
  const int xcd  = s & 7;
  const int ss   = s >> 3;
  const int pass = mpx << 1;
  const int ng   = ss / pass;
  const int rem  = ss - ng * pass;
  m_t = xcd * mpx + (rem >> 1);
  n_t = (ng << 1) + (rem & 1);
}

enum { E_EXP = 0, E_BF16 = 1, E_SIG = 2, E_ADD1 = 3, E_SILU = 4, E_F32 = 5, E_SIGADD2 = 6 };

template <int EPI>
__device__ __forceinline__ void epilogue(
    floatx4 acc[4][4], void* Cout, const void* aux1, const void* aux2,
    long m0, long n0, int ldc, int lane, int wm, int wn) {
  const int r0 = wm * 64 + ((lane >> 4) << 2);
  const int c0 = wn * 64 + (lane & 15);
#pragma unroll
  for (int mt = 0; mt < 4; mt++) {
#pragma unroll
    for (int i = 0; i < 4; i++) {
      long r = m0 + r0 + mt * 16 + i;
      long bidx = r * (long)ldc + n0 + c0;
#pragma unroll
      for (int nt = 0; nt < 4; nt++) {
        long idx = bidx + nt * 16;
        float v = acc[mt][nt][i];
        if constexpr (EPI == E_EXP) {
          ((bf16*)Cout)[idx] = f2bf(__expf(fminf(v, 60.f)));
        } else if constexpr (EPI == E_BF16) {
          ((bf16*)Cout)[idx] = f2bf(v);
        } else if constexpr (EPI == E_SIG) {
          ((bf16*)Cout)[idx] = f2bf(1.f / (1.f + __expf(-v)));
        } else if constexpr (EPI == E_ADD1) {
          float prev = ((const float*)aux1)[idx];   // may alias Cout (same idx)
          ((float*)Cout)[idx] = v + prev;
        } else if constexpr (EPI == E_SILU) {
          ((bf16*)Cout)[idx] = f2bf(v / (1.f + __expf(-v)));
        } else if constexpr (EPI == E_F32) {
          ((float*)Cout)[idx] = v;
        } else {  // E_SIGADD2
          float a1 = ((const float*)aux1)[idx];
          float a2 = ((const float*)aux2)[idx];
          ((float*)Cout)[idx] = a1 + 1.f / (1.f + __expf(-v)) + a2;
        }
      }
    }
  }
}

// =====================================================================================
// 256x128-tile GEMM core, BK=64, TRIPLE-buffered LDS (3 x 48 KiB = 144 KiB), 8 waves
// (4M x 2N, 64x64 output each), ONE barrier + ONE counted vmcnt per K-iter.
// (R4-measured version.) Exit state: per-wave vmcnt==0, all own ds-reads drained
// (lgkmcnt(0) precedes final MFMAs) — callers may __syncthreads() and re-run.
// =====================================================================================
__device__ __forceinline__ void mm_core_n128(
    const bf16* __restrict__ A, const bf16* __restrict__ Bt,
    int lda, int ldb, int K, long m0, long n0,
    int wv, int lane, bf16* Lds, floatx4 acc[4][4]) {
  const int rl  = lane >> 2;
  const int scol = (((lane & 3) - ((lane >> 3) & 3)) & 3) * 8;  // phase-swizzled k-slot
  const bf16* gA = A + (m0 + wv * 16 + rl) * (long)lda + scol;
  const bf16* gB = Bt + (n0 + wv * 16 + rl) * (long)ldb + scol;
  bf16* lA = Lds + wv * 512;            // + buf*16384 + h*4096; second k-panel +8192
  bf16* lB = Lds + 49152 + wv * 512;    // + buf*8192;           second k-panel +4096

  const int wm = wv >> 1, wn = wv & 1;
  const int pg = ((lane >> 4) + ((lane >> 1) & 3)) & 3;
  const bf16* fa0 = Lds + (wm * 64 + (lane & 15)) * 32 + pg * 8;
  const bf16* fb0 = Lds + 49152 + (wn * 64 + (lane & 15)) * 32 + pg * 8;

#define STGA_N(buf, h, kt) do { \
    const bf16* _s = gA + (long)(h) * 128 * lda + (long)(kt) * 64; \
    bf16* _d = lA + (buf) * 16384 + (h) * 4096; \
    gld_lds(_s, _d); gld_lds(_s + 32, _d + 8192); } while (0)
#define STGB_N(buf, kt) do { \
    const bf16* _s = gB + (long)(kt) * 64; \
    bf16* _d = lB + (buf) * 8192; \
    gld_lds(_s, _d); gld_lds(_s + 32, _d + 4096); } while (0)

  STGA_N(0, 0, 0); STGA_N(0, 1, 0); STGB_N(0, 0);
  STGA_N(1, 0, 1); STGA_N(1, 1, 1); STGB_N(1, 1);
  asm volatile("s_waitcnt vmcnt(6)" ::: "memory");
  __builtin_amdgcn_s_barrier();

  const int niter = K >> 6;            // K % 64 == 0
  int p = 0;
  for (int it = 0; it < niter; ++it) {
    const int q = (p >= 1) ? p - 1 : p + 2;      // (p+2)%3
    const bool dostage = (it <= niter - 3);
    const bf16* fa = fa0 + p * 16384;
    const bf16* fb = fb0 + p * 8192;

    // ---- kh = 0 ----
    bf16x8 a0[4], b0v[4];
#pragma unroll
    for (int i = 0; i < 4; ++i) {
      a0[i]  = *(const bf16x8*)(fa + i * 512);
      b0v[i] = *(const bf16x8*)(fb + i * 512);
    }
    __builtin_amdgcn_sched_barrier(0);
    if (dostage) { STGA_N(q, 0, it + 2); STGA_N(q, 1, it + 2); }
    asm volatile("s_waitcnt lgkmcnt(0)" ::: "memory");
    __builtin_amdgcn_s_setprio(1);
#pragma unroll
    for (int mf = 0; mf < 4; ++mf)
#pragma unroll
      for (int nf = 0; nf < 4; ++nf)
        acc[mf][nf] = __builtin_amdgcn_mfma_f32_16x16x32_bf16(a0[mf], b0v[nf], acc[mf][nf], 0, 0, 0);
    __builtin_amdgcn_s_setprio(0);

    // ---- kh = 1 ----
    bf16x8 a1[4], b1v[4];
#pragma unroll
    for (int i = 0; i < 4; ++i) {
      a1[i]  = *(const bf16x8*)(fa + 8192 + i * 512);
      b1v[i] = *(const bf16x8*)(fb + 4096 + i * 512);
    }
    __builtin_amdgcn_sched_barrier(0);
    if (dostage) STGB_N(q, it + 2);
    asm volatile("s_waitcnt lgkmcnt(0)" ::: "memory");
    __builtin_amdgcn_s_setprio(1);
#pragma unroll
    for (int mf = 0; mf < 4; ++mf)
#pragma unroll
      for (int nf = 0; nf < 4; ++nf)
        acc[mf][nf] = __builtin_amdgcn_mfma_f32_16x16x32_bf16(a1[mf], b1v[nf], acc[mf][nf], 0, 0, 0);
    __builtin_amdgcn_s_setprio(0);

    if (it < niter - 1) {
      if (dostage) asm volatile("s_waitcnt vmcnt(6)" ::: "memory");
      else         asm volatile("s_waitcnt vmcnt(0)" ::: "memory");
      __builtin_amdgcn_s_barrier();
    }
    p = (p == 2) ? 0 : p + 1;
  }
#undef STGA_N
#undef STGB_N
}

// 256x128-tile kernel: grid = (M/256)*(N/128) blocks.
template <int EPI>
__global__ __launch_bounds__(512, 2) void gemm8n(
    const bf16* __restrict__ A, const bf16* __restrict__ Bt,
    void* Cout, const void* aux1, const void* aux2,
    int lda, int ldb, int ldc, int K, int gm, int gn) {
  __shared__ __align__(16) bf16 Lds[73728];   // 144 KiB
  const int tid = threadIdx.x;
  const int lane = tid & 63;
  const int wv = tid >> 6;
  int m_t, n_t;
  swz(blockIdx.x, gm, m_t, n_t);
  const long m0 = (long)m_t * 256, n0 = (long)n_t * 128;
  floatx4 acc[4][4];
#pragma unroll
  for (int i = 0; i < 4; i++)
#pragma unroll
    for (int j = 0; j < 4; j++) acc[i][j] = (floatx4){0.f, 0.f, 0.f, 0.f};
  mm_core_n128(A, Bt, lda, ldb, K, m0, n0, wv, lane, Lds, acc);
  const int wm = wv >> 1, wn = wv & 1;   // 4M x 2N waves, 64x64 each
  epilogue<EPI>(acc, Cout, aux1, aux2, m0, n0, ldc, lane, wm, wn);
}

// ---------------- dual GEMM: d_out = xres + sigmoid(xr2@cWr) + hbuf@cWv ----------------
// Two back-to-back n128 cores on the same output tile; acc1 held in VGPRs across core-2.
// __syncthreads() between cores: core-1 exits with vmcnt=0 per-wave and its ds-reads
// drained, so the barrier makes LDS reuse by core-2's prologue race-free.
__global__ __launch_bounds__(512, 2) void gemm_dual(
    const bf16* __restrict__ A1, const bf16* __restrict__ Bt1,   // hbuf [M,HU], cWvT [H,HU]
    const bf16* __restrict__ A2, const bf16* __restrict__ Bt2,   // xr2 [M,H],  cWrT [H,H]
    float* __restrict__ Cout, const float* __restrict__ xres,
    int gm, int gn) {
  __shared__ __align__(16) bf16 Lds[73728];   // 144 KiB
  const int tid = threadIdx.x;
  const int lane = tid & 63;
  const int wv = tid >> 6;
  int m_t, n_t;
  swz(blockIdx.x, gm, m_t, n_t);
  const long m0 = (long)m_t * 256, n0 = (long)n_t * 128;

  floatx4 acc1[4][4], acc2[4][4];
#pragma unroll
  for (int i = 0; i < 4; i++)
#pragma unroll
    for (int j = 0; j < 4; j++) {
      acc1[i][j] = (floatx4){0.f, 0.f, 0.f, 0.f};
      acc2[i][j] = (floatx4){0.f, 0.f, 0.f, 0.f};
    }

  mm_core_n128(A1, Bt1, HUdim, HUdim, HUdim, m0, n0, wv, lane, Lds, acc1);
  __syncthreads();
  mm_core_n128(A2, Bt2, Hdim, Hdim, Hdim, m0, n0, wv, lane, Lds, acc2);

  const int wm = wv >> 1, wn = wv & 1;
  const int r0 = wm * 64 + ((lane >> 4) << 2);
  const int c0 = wn * 64 + (lane & 15);
#pragma unroll
  for (int mt = 0; mt < 4; ++mt) {
#pragma unroll
    for (int i = 0; i < 4; ++i) {
      long r = m0 + r0 + mt * 16 + i;
      long bidx = r * (long)Hdim + n0 + c0;
#pragma unroll
      for (int nt = 0; nt < 4; ++nt) {
        long idx = bidx + nt * 16;
        float vr = acc2[mt][nt][i];
        Cout[idx] = xres[idx] + 1.f / (1.f + __expf(-vr)) + acc1[mt][nt][i];
      }
    }
  }
}

// =====================================================================================
// 8-phase 256x256 GEMM core (zigzag quadrant order) — R2/R4-measured version.
// =====================================================================================
__device__ __forceinline__ void mm_core256(
    const bf16* __restrict__ A, const bf16* __restrict__ Bt,
    int lda, int ldb, int K, long m0, long n0,
    int wv, int lane, bf16* Lds, floatx4 acc[8][4]) {
  const int wm = wv >> 2, wn = wv & 3;
  const int rA0 = wm * 128 + (wv & 3) * 16;
  const int rB0 = (wv >> 1) * 64 + (wv & 1) * 16;
  const int rl  = lane >> 2;
  const int scol = (((lane & 3) - ((lane >> 3) & 3)) & 3) * 8;
  const bf16* gA = A + (m0 + rA0 + rl) * (long)lda + scol;
  const bf16* gB = Bt + (n0 + rB0 + rl) * (long)ldb + scol;
  bf16* lA = Lds + rA0 * 32;
  bf16* lB = Lds + 16384 + rB0 * 32;

  const int pg = ((lane >> 4) + ((lane >> 1) & 3)) & 3;
  const bf16* fa0 = Lds + (wm * 128 + (lane & 15)) * 32 + pg * 8;
  const bf16* fb0 = Lds + 16384 + (wn * 64 + (lane & 15)) * 32 + pg * 8;

#define STGA8(buf, h, kt) do { \
    const bf16* _s = gA + (long)(h) * 64 * lda + (kt) * 64; \
    bf16* _d = lA + (buf) * 32768 + (h) * 2048; \
    gld_lds(_s, _d); gld_lds(_s + 32, _d + 8192); } while (0)
#define STGB8(buf, h, kt) do { \
    const bf16* _s = gB + (long)(h) * 32 * ldb + (kt) * 64; \
    bf16* _d = lB + (buf) * 32768 + (h) * 1024; \
    gld_lds(_s, _d); gld_lds(_s + 32, _d + 8192); } while (0)

  STGA8(0, 0, 0); STGB8(0, 0, 0); STGB8(0, 1, 0); STGA8(0, 1, 0);
  STGA8(1, 0, 1); STGB8(1, 0, 1); STGB8(1, 1, 1);
  asm volatile("s_waitcnt vmcnt(10)" ::: "memory");
  __builtin_amdgcn_s_barrier();

  const int niter = K >> 7;            // K % 128 == 0
  bf16x8 a[4][2];
  bf16x8 b[2][2][2];
  for (int it = 0; it < niter; ++it) {
    const int kt0 = it << 1;
    const bool notlast = (it != niter - 1);
#pragma unroll
    for (int ph = 0; ph < 8; ++ph) {
      const int q   = ph & 3;
      const int buf = ph >> 2;
      const int mq  = q >> 1;
      const int nq  = (q >> 1) ^ (q & 1);
      const bf16* fa = fa0 + buf * 32768 + mq * 2048;
      const bf16* fb = fb0 + buf * 32768 + nq * 1024;
      if (q == 0) {
#pragma unroll
        for (int mf = 0; mf < 4; ++mf) {
          a[mf][0] = *(const bf16x8*)(fa + mf * 512);
          a[mf][1] = *(const bf16x8*)(fa + mf * 512 + 8192);
        }
#pragma unroll
        for (int nf = 0; nf < 2; ++nf) {
          b[0][nf][0] = *(const bf16x8*)(fb + nf * 512);
          b[0][nf][1] = *(const bf16x8*)(fb + nf * 512 + 8192);
        }
      } else if (q == 1) {
#pragma unroll
        for (int nf = 0; nf < 2; ++nf) {
          b[1][nf][0] = *(const bf16x8*)(fb + nf * 512);
          b[1][nf][1] = *(const bf16x8*)(fb + nf * 512 + 8192);
        }
      } else if (q == 2) {
#pragma unroll
        for (int mf = 0; mf < 4; ++mf) {
          a[mf][0] = *(const bf16x8*)(fa + mf * 512);
          a[mf][1] = *(const bf16x8*)(fa + mf * 512 + 8192);
        }
      }
      __builtin_amdgcn_sched_barrier(0);
      if (ph == 0)            STGA8(1, 1, kt0 + 1);
      else if (notlast) {
        if (ph == 1)      STGA8(0, 0, kt0 + 2);
        else if (ph == 2) STGB8(0, 0, kt0 + 2);
        else if (ph == 3) STGB8(0, 1, kt0 + 2);
        else if (ph == 4) STGA8(0, 1, kt0 + 2);
        else if (ph == 5) STGA8(1, 0, kt0 + 3);
        else if (ph == 6) STGB8(1, 0, kt0 + 3);
        else              STGB8(1, 1, kt0 + 3);
      }
      if (notlast) {
        if (ph == 0 || ph == 1 || ph == 4 || ph == 5)
          asm volatile("s_waitcnt vmcnt(10)" ::: "memory");
        else if (ph == 3 || ph == 7)
          asm volatile("s_waitcnt vmcnt(12)" ::: "memory");
      } else {
        if (ph == 0)      asm volatile("s_waitcnt vmcnt(10)" ::: "memory");
        else if (ph == 1) asm volatile("s_waitcnt vmcnt(0)" ::: "memory");
      }
      if (q != 3) {
        __builtin_amdgcn_s_barrier();
        asm volatile("s_waitcnt lgkmcnt(0)" ::: "memory");
      }
      __builtin_amdgcn_s_setprio(1);
#pragma unroll
      for (int mf = 0; mf < 4; ++mf)
#pragma unroll
        for (int nf = 0; nf < 2; ++nf) {
          acc[mq*4+mf][nq*2+nf] = __builtin_amdgcn_mfma_f32_16x16x32_bf16(
              a[mf][0], b[nq][nf][0], acc[mq*4+mf][nq*2+nf], 0, 0, 0);
          acc[mq*4+mf][nq*2+nf] = __builtin_amdgcn_mfma_f32_16x16x32_bf16(
              a[mf][1], b[nq][nf][1], acc[mq*4+mf][nq*2+nf], 0, 0, 0);
        }
      __builtin_amdgcn_s_setprio(0);
      __builtin_amdgcn_s_barrier();
    }
  }
#undef STGA8
#undef STGB8
}

template <int EPI>
__global__ __launch_bounds__(512, 2) void gemm8(
    const bf16* __restrict__ A, const bf16* __restrict__ Bt,
    void* Cout, const void* aux1, const void* aux2,
    int lda, int ldb, int ldc, int K, int gm, int gn) {
  __shared__ __align__(16) bf16 Lds[65536];   // 128 KiB
  const int tid = threadIdx.x;
  const int lane = tid & 63;
  const int wv = tid >> 6;
  int m_t, n_t;
  swz(blockIdx.x, gm, m_t, n_t);
  const long m0 = (long)m_t * 256, n0 = (long)n_t * 256;
  floatx4 acc[8][4];
#pragma unroll
  for (int i = 0; i < 8; i++)
#pragma unroll
    for (int j = 0; j < 4; j++) acc[i][j] = (floatx4){0.f, 0.f, 0.f, 0.f};
  mm_core256(A, Bt, lda, ldb, K, m0, n0, wv, lane, Lds, acc);

  const int wm = wv >> 2, wn = wv & 3;
  const int r0 = wm * 128 + ((lane >> 4) << 2);
  const int c0 = wn * 64 + (lane & 15);
#pragma unroll
  for (int mf = 0; mf < 8; ++mf) {
#pragma unroll
    for (int i = 0; i < 4; ++i) {
      long r = m0 + r0 + mf * 16 + i;
      long bidx = r * (long)ldc + n0 + c0;
#pragma unroll
      for (int nf = 0; nf < 4; ++nf) {
        long idx = bidx + nf * 16;
        float v = acc[mf][nf][i];
        if constexpr (EPI == E_SILU) {
          ((bf16*)Cout)[idx] = f2bf(v / (1.f + __expf(-v)));
        } else if constexpr (EPI == E_BF16) {
          ((bf16*)Cout)[idx] = f2bf(v);
        } else if constexpr (EPI == E_F32) {
          ((float*)Cout)[idx] = v;
        } else if constexpr (EPI == E_ADD1) {
          float prev = ((const float*)aux1)[idx];
          ((float*)Cout)[idx] = v + prev;
        }
      }
    }
  }
}

// ---------------- fused K/V/R projection on the 8-phase core ----------------
__global__ __launch_bounds__(512, 2) void proj8(
    const bf16* __restrict__ xk, const bf16* __restrict__ xv, const bf16* __restrict__ xr,
    const bf16* __restrict__ Wk, const bf16* __restrict__ Wv, const bf16* __restrict__ Wr,
    bf16* Kc, bf16* Vc, bf16* SRc, int gm, int gn) {
  __shared__ __align__(16) bf16 Lds[65536];   // 128 KiB
  const int per = gm * gn;
  const int sub = blockIdx.x / per;           // 0:K 1:V 2:R
  const int s   = blockIdx.x - sub * per;
  const int tid = threadIdx.x;
  const int lane = tid & 63;
  const int wv = tid >> 6;
  int m_t, n_t;
  swz(s, gm, m_t, n_t);
  const long m0 = (long)m_t * 256, n0 = (long)n_t * 256;

  const bf16* A  = (sub == 0) ? xk : (sub == 1) ? xv : xr;
  const bf16* Bt = (sub == 0) ? Wk : (sub == 1) ? Wv : Wr;
  bf16*       C  = (sub == 0) ? Kc : (sub == 1) ? Vc : SRc;

  floatx4 acc[8][4];
#pragma unroll
  for (int i = 0; i < 8; i++)
#pragma unroll
    for (int j = 0; j < 4; j++) acc[i][j] = (floatx4){0.f, 0.f, 0.f, 0.f};
  mm_core256(A, Bt, Hdim, Hdim, Hdim, m0, n0, wv, lane, Lds, acc);

  const int wm = wv >> 2, wn = wv & 3;
  const int r0 = wm * 128 + ((lane >> 4) << 2);
  const int c0 = wn * 64 + (lane & 15);
#pragma unroll
  for (int mf = 0; mf < 8; ++mf) {
#pragma unroll
    for (int i = 0; i < 4; ++i) {
      long r = m0 + r0 + mf * 16 + i;
      long bidx = r * (long)CHUNK + n0 + c0;
#pragma unroll
      for (int nf = 0; nf < 4; ++nf) {
        long idx = bidx + nf * 16;
        float v = acc[mf][nf][i];
        float o;
        if (sub == 0)      o = __expf(fminf(v, 60.f));
        else if (sub == 1) o = v;
        else               o = 1.f / (1.f + __expf(-v));
        C[idx] = f2bf(o);
      }
    }
  }
}

// ---------------- launch ----------------
extern "C" void kernel_launch(void* const* d_in, const int* in_sizes, int n_in,
                              void* d_out, int out_size, void* d_ws, size_t ws_size,
                              hipStream_t stream) {
  (void)in_sizes; (void)n_in; (void)out_size; (void)ws_size;
  const float* x        = (const float*)d_in[0];
  const float* ln0_g    = (const float*)d_in[1];
  const float* ln0_b    = (const float*)d_in[2];
  const float* pre_g    = (const float*)d_in[3];
  const float* pre_b    = (const float*)d_in[4];
  const float* post_g   = (const float*)d_in[5];
  const float* post_b   = (const float*)d_in[6];
  const float* tm_decay = (const float*)d_in[7];
  const float* tm_first = (const float*)d_in[8];
  const float* tm_mix_k = (const float*)d_in[9];
  const float* tm_mix_v = (const float*)d_in[10];
  const float* tm_mix_r = (const float*)d_in[11];
  const float* tm_Wk    = (const float*)d_in[12];
  const float* tm_Wv    = (const float*)d_in[13];
  const float* tm_Wr    = (const float*)d_in[14];
  const float* tm_Wo    = (const float*)d_in[15];
  const float* cm_mix_k = (const float*)d_in[16];
  const float* cm_mix_r = (const float*)d_in[17];
  const float* cm_Wk    = (const float*)d_in[18];
  const float* cm_Wv    = (const float*)d_in[19];
  const float* cm_Wr    = (const float*)d_in[20];

  char* ws = (char*)d_ws;
  // static layout (bytes); peak 239,075,328 (228 MiB; stK/stKV doubled for NSEG=32)
  bf16*  WkT  = (bf16*)(ws + 0);          // [HU,H]
  bf16*  WvT  = (bf16*)(ws + 8388608);    // [HU,H]
  bf16*  WrT  = (bf16*)(ws + 16777216);   // [HU,H]
  bf16*  WoT  = (bf16*)(ws + 25165824);   // [H,HU]
  bf16*  cWkT = (bf16*)(ws + 33554432);   // [HU,H]
  bf16*  cWvT = (bf16*)(ws + 41943040);   // [H,HU]
  bf16*  cWrT = (bf16*)(ws + 50331648);   // [H,H]
  float* xres = (float*)(ws + 52428800);  // [M,H] f32
  bf16*  xk   = (bf16*)(ws + 85983232);   // [M,H]
  bf16*  xv   = (bf16*)(ws + 102760448);
  bf16*  xr   = (bf16*)(ws + 119537664);
  bf16*  Kc   = (bf16*)(ws + 136314880);  // [M,CHUNK]
  bf16*  Vc   = (bf16*)(ws + 169869312);  // [M,CHUNK]
  bf16*  SRc  = (bf16*)(ws + 203423744);  // [M,CHUNK], P written in place
  float* stK  = (float*)(ws + 236978176); // [NSEG,B,CHUNK] f32 (1 MiB)
  float* stKV = (float*)(ws + 238026752); // [NSEG,B,CHUNK] f32 (1 MiB)
  // CM-phase aliases (regions dead by then):
  bf16*  xk2  = (bf16*)(ws + 136314880);  // over Kc
  bf16*  xr2  = (bf16*)(ws + 153092096);  // over Kc (2nd half)
  bf16*  hbuf = (bf16*)(ws + 169869312);  // [M,HU] over Vc+SRc

  dim3 blk(256);
  wconv_all<<<6400, blk, 0, stream>>>(tm_Wk, tm_Wv, tm_Wr, tm_Wo, cm_Wk, cm_Wv, cm_Wr,
                                      WkT, WvT, WrT, WoT, cWkT, cWvT, cWrT);

  ln_mix_tm<<<Mrows, blk, 0, stream>>>(x, ln0_g, ln0_b, pre_g, pre_b,
                                       tm_mix_k, tm_mix_v, tm_mix_r, xres, xk, xv, xr);

  const int scan_grid = NSEG * Bdim * (CHUNK / 128);  // 2048 blocks (2 ch/thread)
  const int GM8 = Mrows / 256;                         // 32 (256-row tiles)
  const int GN8p = CHUNK / 256;                        // 8
  const int GNn = Hdim / 128;                          // 8 (gemm8n n-tiles)
  for (int ch = 0; ch < NCH; ch++) {
    const long woff = (long)ch * CHUNK;
    // 3 fused GEMMs on the 8-phase 256^2 core: 768 blocks = 3 full waves of 256 CUs
    proj8<<<3 * GM8 * GN8p, dim3(512), 0, stream>>>(
        xk, xv, xr, WkT + woff * Hdim, WvT + woff * Hdim, WrT + woff * Hdim,
        Kc, Vc, SRc, GM8, GN8p);

    wkv_part<<<scan_grid, dim3(64), 0, stream>>>(
        Kc, Vc, stK, stKV, tm_decay + woff);
    wkv_emit<<<scan_grid, dim3(64), 0, stream>>>(
        Kc, Vc, SRc, SRc, stK, stKV, tm_decay + woff, tm_first + woff);

    // xres += P_ch @ Wo[ch*CHUNK:,:]  -> 256x128-tile one-barrier core, 256 blocks
    gemm8n<E_ADD1><<<GM8 * GNn, dim3(512), 0, stream>>>(
        SRc, WoT + woff, xres, xres, nullptr, CHUNK, HUdim, Hdim, CHUNK, GM8, GNn);
  }

  ln_mix_cm<<<Mrows, blk, 0, stream>>>(xres, post_g, post_b, cm_mix_k, cm_mix_r, xk2, xr2);

  // hbuf = silu(xk2 @ cWk) over full HU on the 8-phase core: 512 blocks
  gemm8<E_SILU><<<GM8 * (HUdim/256), dim3(512), 0, stream>>>(
      xk2, cWkT, hbuf, nullptr, nullptr, Hdim, Hdim, HUdim, Hdim, GM8, HUdim/256);

  // d_out = xres + sigmoid(xr2 @ cWr) + hbuf @ cWv  — ONE fused dual-K kernel
  gemm_dual<<<GM8 * GNn, dim3(512), 0, stream>>>(
      hbuf, cWvT, xr2, cWrT, (float*)d_out, xres, GM8, GNn);
}